// Round 1
// baseline (623.935 us; speedup 1.0000x reference)
//
#include <hip/hip_runtime.h>
#include <math.h>

#define EPS 1e-5f

__device__ __forceinline__ float elu_f(float x) {
    return x > 0.f ? x : __expf(x) - 1.f;
}

// ---------------- Kernel 1: e = elu(z @ W_emb^T + b_emb) ----------------
// grid.x = (800/8)*2 = 200 ; block = 256
// Each block: one src (z0 or z1), 8 rows. LDS-stage 8x1024 floats.
// Active threads t<200: d = t%100, half = t/100 (4 rows each).
__global__ __launch_bounds__(256) void kembed(const float* __restrict__ z0,
                                              const float* __restrict__ z1,
                                              const float* __restrict__ Wemb,
                                              const float* __restrict__ bemb,
                                              float* __restrict__ e0,
                                              float* __restrict__ e1) {
    __shared__ float4 zs4[2048];  // 8 rows x 1024 floats
    int src = blockIdx.x & 1;
    int rowbase = (blockIdx.x >> 1) * 8;
    const float* z = src ? z1 : z0;
    float* e = src ? e1 : e0;
    const float4* zrow4 = reinterpret_cast<const float4*>(z + rowbase * 1024);
    for (int idx = threadIdx.x; idx < 2048; idx += 256) zs4[idx] = zrow4[idx];
    __syncthreads();
    int t = threadIdx.x;
    if (t < 200) {
        int d = t % 100;
        int half = t / 100;
        const float4* w4 = reinterpret_cast<const float4*>(Wemb + d * 1024);
        float acc[4] = {0.f, 0.f, 0.f, 0.f};
        for (int k = 0; k < 256; k++) {
            float4 w = w4[k];
#pragma unroll
            for (int r = 0; r < 4; r++) {
                float4 zv = zs4[(half * 4 + r) * 256 + k];
                acc[r] = fmaf(w.x, zv.x, acc[r]);
                acc[r] = fmaf(w.y, zv.y, acc[r]);
                acc[r] = fmaf(w.z, zv.z, acc[r]);
                acc[r] = fmaf(w.w, zv.w, acc[r]);
            }
        }
        float be = bemb[d];
#pragma unroll
        for (int r = 0; r < 4; r++) {
            e[(rowbase + half * 4 + r) * 100 + d] = elu_f(acc[r] + be);
        }
    }
}

// ---------------- Kernel 2: interaction + bias + elu + bn1 + elu ----------------
// grid (50,50); block 256. Tile 16x16 (i,j) pairs; each thread one pair, acc[50].
// Bmap[h][i][j] written (50 x 800 x 800).
__global__ __launch_bounds__(256) void kinter(const float* __restrict__ e0,
                                              const float* __restrict__ e1,
                                              const float* __restrict__ W1,
                                              const float* __restrict__ b1,
                                              const float* __restrict__ g1,
                                              const float* __restrict__ bb1,
                                              const float* __restrict__ m1,
                                              const float* __restrict__ v1,
                                              float* __restrict__ Bmap) {
    __shared__ float e0s[1600];
    __shared__ float e1s[1600];
    int ti = blockIdx.x;
    int tj = blockIdx.y;
    int tid = threadIdx.x;
    for (int idx = tid; idx < 1600; idx += 256) {
        e0s[idx] = e0[ti * 1600 + idx];
        e1s[idx] = e1[tj * 1600 + idx];
    }
    __syncthreads();
    int li = tid >> 4, lj = tid & 15;
    const float* e0r = &e0s[li * 100];
    const float* e1r = &e1s[lj * 100];
    float acc[50];
#pragma unroll
    for (int h = 0; h < 50; h++) acc[h] = 0.f;
    for (int d = 0; d < 100; d++) {
        float a0 = e0r[d];
        float a1 = e1r[d];
        float dif = fabsf(a0 - a1);
        float mul = a0 * a1;
#pragma unroll
        for (int h = 0; h < 50; h++) {
            acc[h] = fmaf(W1[h * 200 + d], dif, acc[h]);
            acc[h] = fmaf(W1[h * 200 + 100 + d], mul, acc[h]);
        }
    }
    int i = ti * 16 + li, j = tj * 16 + lj;
    size_t base = (size_t)i * 800 + j;
#pragma unroll
    for (int h = 0; h < 50; h++) {
        float x = acc[h] + b1[h];
        x = elu_f(x);
        float sc = g1[h] * rsqrtf(v1[h] + EPS);
        x = (x - m1[h]) * sc + bb1[h];
        x = elu_f(x);
        Bmap[(size_t)h * 640000 + base] = x;
    }
}

// ---------------- Kernel 3: 7x7 conv over 50 channels + b2 + bn2 ----------------
// grid (25,25); block 256. 32x32 output tile, 4 outputs/thread (consecutive j).
__global__ __launch_bounds__(256) void kconv(const float* __restrict__ Bmap,
                                             const float* __restrict__ W2,
                                             const float* __restrict__ b2,
                                             const float* __restrict__ g2,
                                             const float* __restrict__ bb2,
                                             const float* __restrict__ m2,
                                             const float* __restrict__ v2,
                                             float* __restrict__ C) {
    __shared__ float tile[38][40];   // padded rows (160B -> float4 aligned)
    __shared__ float w2s[50][49];
    int ti = blockIdx.y, tj = blockIdx.x;
    int tid = threadIdx.x;
    for (int idx = tid; idx < 2450; idx += 256) w2s[idx / 49][idx % 49] = W2[idx];
    int ly = tid >> 3;      // 0..31
    int lx = tid & 7;       // 0..7
    int i0 = ti * 32 + ly;
    int j0 = tj * 32 + lx * 4;
    float acc[4] = {0.f, 0.f, 0.f, 0.f};
    for (int h = 0; h < 50; h++) {
        __syncthreads();
        const float* plane = Bmap + (size_t)h * 640000;
        for (int idx = tid; idx < 38 * 38; idx += 256) {
            int r = idx / 38, c = idx % 38;
            int gy = ti * 32 - 3 + r;
            int gx = tj * 32 - 3 + c;
            float val = 0.f;
            if (gy >= 0 && gy < 800 && gx >= 0 && gx < 800) val = plane[gy * 800 + gx];
            tile[r][c] = val;
        }
        __syncthreads();
#pragma unroll
        for (int di = 0; di < 7; di++) {
            const float* trow = &tile[ly + di][lx * 4];
            float4 ra = *(const float4*)(trow);
            float4 rb = *(const float4*)(trow + 4);
            float rv[10] = {ra.x, ra.y, ra.z, ra.w, rb.x, rb.y, rb.z, rb.w,
                            trow[8], trow[9]};
#pragma unroll
            for (int dj = 0; dj < 7; dj++) {
                float w = w2s[h][di * 7 + dj];
                acc[0] = fmaf(rv[dj + 0], w, acc[0]);
                acc[1] = fmaf(rv[dj + 1], w, acc[1]);
                acc[2] = fmaf(rv[dj + 2], w, acc[2]);
                acc[3] = fmaf(rv[dj + 3], w, acc[3]);
            }
        }
    }
    float s2 = g2[0] * rsqrtf(v2[0] + EPS);
    float t2 = bb2[0] - m2[0] * s2;
    float bias = b2[0];
    float4 out;
    out.x = (acc[0] + bias) * s2 + t2;
    out.y = (acc[1] + bias) * s2 + t2;
    out.z = (acc[2] + bias) * s2 + t2;
    out.w = (acc[3] + bias) * s2 + t2;
    *(float4*)&C[(size_t)i0 * 800 + j0] = out;
}

// ---------------- Kernel 4: 9x9/9 maxpool with pad 4 -> yhat (89x89) ----------------
__global__ __launch_bounds__(256) void kpool(const float* __restrict__ C,
                                             float* __restrict__ yhat) {
    int idx = blockIdx.x * 256 + threadIdx.x;
    if (idx >= 89 * 89) return;
    int oy = idx / 89, ox = idx % 89;
    float mx = -INFINITY;
    int y0 = oy * 9 - 4, x0 = ox * 9 - 4;
    for (int dy = 0; dy < 9; dy++) {
        int y = y0 + dy;
        if (y < 0 || y >= 800) continue;
        for (int dx = 0; dx < 9; dx++) {
            int x = x0 + dx;
            if (x < 0 || x >= 800) continue;
            mx = fmaxf(mx, C[y * 800 + x]);
        }
    }
    yhat[idx] = mx;
}

// ---------------- Kernel 5: mean/var -> Q -> phat -> gelu ----------------
__global__ __launch_bounds__(256) void kfinal(const float* __restrict__ yhat,
                                              const float* __restrict__ gamma,
                                              float* __restrict__ out) {
    const int N = 89 * 89;
    __shared__ float sA[4], sB[4];
    int tid = threadIdx.x;
    int wid = tid >> 6, lane = tid & 63;
    float s = 0.f, ss = 0.f;
    for (int i = tid; i < N; i += 256) {
        float y = yhat[i];
        s += y;
        ss = fmaf(y, y, ss);
    }
    for (int off = 32; off; off >>= 1) {
        s += __shfl_down(s, off);
        ss += __shfl_down(ss, off);
    }
    if (lane == 0) { sA[wid] = s; sB[wid] = ss; }
    __syncthreads();
    float S = sA[0] + sA[1] + sA[2] + sA[3];
    float SS = sB[0] + sB[1] + sB[2] + sB[3];
    float mu = S / (float)N;
    float var = (SS - S * S / (float)N) / (float)(N - 1);
    float thr = mu + gamma[0] * var;
    __syncthreads();
    float q = 0.f, c = 0.f;
    for (int i = tid; i < N; i += 256) {
        float d = yhat[i] - thr;
        if (d > 0.f) { q += d; c += 1.f; }
    }
    for (int off = 32; off; off >>= 1) {
        q += __shfl_down(q, off);
        c += __shfl_down(c, off);
    }
    if (lane == 0) { sA[wid] = q; sB[wid] = c; }
    __syncthreads();
    if (tid == 0) {
        float Q = sA[0] + sA[1] + sA[2] + sA[3];
        float Cnt = sB[0] + sB[1] + sB[2] + sB[3];
        float phat = Q / (Cnt + 1.f);
        out[0] = 0.5f * phat * (1.f + erff(phat * 0.70710678118654752f));
    }
}

extern "C" void kernel_launch(void* const* d_in, const int* in_sizes, int n_in,
                              void* d_out, int out_size, void* d_ws, size_t ws_size,
                              hipStream_t stream) {
    const float* z0   = (const float*)d_in[0];
    const float* z1   = (const float*)d_in[1];
    const float* Wemb = (const float*)d_in[2];
    const float* bemb = (const float*)d_in[3];
    const float* W1   = (const float*)d_in[4];
    const float* b1   = (const float*)d_in[5];
    const float* bn1g = (const float*)d_in[6];
    const float* bn1b = (const float*)d_in[7];
    const float* bn1m = (const float*)d_in[8];
    const float* bn1v = (const float*)d_in[9];
    const float* W2   = (const float*)d_in[10];
    const float* b2   = (const float*)d_in[11];
    const float* bn2g = (const float*)d_in[12];
    const float* bn2b = (const float*)d_in[13];
    const float* bn2m = (const float*)d_in[14];
    const float* bn2v = (const float*)d_in[15];
    const float* gam  = (const float*)d_in[16];

    float* ws   = (float*)d_ws;
    float* e0   = ws;                       // 80000
    float* e1   = ws + 80000;               // 80000
    float* Bmap = ws + 160000;              // 32,000,000
    float* C    = ws + 160000 + 32000000;   // 640,000
    float* yhat = C + 640000;               // 7921
    float* out  = (float*)d_out;

    kembed<<<200, 256, 0, stream>>>(z0, z1, Wemb, bemb, e0, e1);
    dim3 gi(50, 50);
    kinter<<<gi, 256, 0, stream>>>(e0, e1, W1, b1, bn1g, bn1b, bn1m, bn1v, Bmap);
    dim3 gc(25, 25);
    kconv<<<gc, 256, 0, stream>>>(Bmap, W2, b2, bn2g, bn2b, bn2m, bn2v, C);
    kpool<<<(89 * 89 + 255) / 256, 256, 0, stream>>>(C, yhat);
    kfinal<<<1, 256, 0, stream>>>(yhat, gam, out);
}

// Round 2
// 392.829 us; speedup vs baseline: 1.5883x; 1.5883x over previous
//
#include <hip/hip_runtime.h>
#include <math.h>

#define EPS 1e-5f

typedef __bf16 bf16x8 __attribute__((ext_vector_type(8)));
typedef float f32x4 __attribute__((ext_vector_type(4)));

__device__ __forceinline__ float elu_f(float x) {
    return x > 0.f ? x : __expf(x) - 1.f;
}

// ---------------- Kernel 1: e = elu(z @ W_emb^T + b_emb) ----------------
__global__ __launch_bounds__(256) void kembed(const float* __restrict__ z0,
                                              const float* __restrict__ z1,
                                              const float* __restrict__ Wemb,
                                              const float* __restrict__ bemb,
                                              float* __restrict__ e0,
                                              float* __restrict__ e1) {
    __shared__ float4 zs4[2048];  // 8 rows x 1024 floats
    int src = blockIdx.x & 1;
    int rowbase = (blockIdx.x >> 1) * 8;
    const float* z = src ? z1 : z0;
    float* e = src ? e1 : e0;
    const float4* zrow4 = reinterpret_cast<const float4*>(z + rowbase * 1024);
    for (int idx = threadIdx.x; idx < 2048; idx += 256) zs4[idx] = zrow4[idx];
    __syncthreads();
    int t = threadIdx.x;
    if (t < 200) {
        int d = t % 100;
        int half = t / 100;
        const float4* w4 = reinterpret_cast<const float4*>(Wemb + d * 1024);
        float acc[4] = {0.f, 0.f, 0.f, 0.f};
        for (int k = 0; k < 256; k++) {
            float4 w = w4[k];
#pragma unroll
            for (int r = 0; r < 4; r++) {
                float4 zv = zs4[(half * 4 + r) * 256 + k];
                acc[r] = fmaf(w.x, zv.x, acc[r]);
                acc[r] = fmaf(w.y, zv.y, acc[r]);
                acc[r] = fmaf(w.z, zv.z, acc[r]);
                acc[r] = fmaf(w.w, zv.w, acc[r]);
            }
        }
        float be = bemb[d];
#pragma unroll
        for (int r = 0; r < 4; r++) {
            e[(rowbase + half * 4 + r) * 100 + d] = elu_f(acc[r] + be);
        }
    }
}

// ---------------- Prep: pack W1 (split hi/lo bf16) into B-fragment order ----------------
// K layout: k in [0,128) -> dif term, d = k ; k in [128,256) -> mul term, d = k-128.
// (d >= 100 or h >= 50 -> 0)
// Fragment order: idx = ((kstep*4 + hfrag)*64 + lane)*8 + i
//   B element for lane: n = h = hfrag*16 + (lane&15), k = kstep*32 + (lane>>4)*8 + i
__global__ __launch_bounds__(256) void kprepW(const float* __restrict__ W1,
                                              unsigned short* __restrict__ Bhi,
                                              unsigned short* __restrict__ Blo) {
    int idx = blockIdx.x * 256 + threadIdx.x;
    if (idx >= 16384) return;
    int i = idx & 7;
    int lane = (idx >> 3) & 63;
    int hf = (idx >> 9) & 3;
    int ks = idx >> 11;
    int h = hf * 16 + (lane & 15);
    int k = ks * 32 + (lane >> 4) * 8 + i;
    int term = k >> 7;
    int d = k & 127;
    float val = (d < 100 && h < 50) ? W1[h * 200 + term * 100 + d] : 0.f;
    unsigned int vb = __float_as_uint(val);
    float hif = __uint_as_float(vb & 0xFFFF0000u);
    Bhi[idx] = (unsigned short)(vb >> 16);
    float lo = val - hif;
    Blo[idx] = __builtin_bit_cast(unsigned short, (__bf16)lo);
}

// ---------------- Kernel 2: interaction GEMM via MFMA (split bf16) ----------------
// grid (50,50), block 256 = 4 waves. Block tile: 16 i x 16 j = 256 pairs, all 64 h (50 real).
// Wave w owns pair-fragments f = 4w..4w+3 (f = i_local). A[row=j_local][k] = feature.
__global__ __launch_bounds__(256) void kinter(const float* __restrict__ e0,
                                              const float* __restrict__ e1,
                                              const unsigned short* __restrict__ Bhi,
                                              const unsigned short* __restrict__ Blo,
                                              const float* __restrict__ b1,
                                              const float* __restrict__ g1,
                                              const float* __restrict__ bb1,
                                              const float* __restrict__ m1,
                                              const float* __restrict__ v1,
                                              float* __restrict__ Bmap) {
    __shared__ float e0s[16][108];
    __shared__ float e1s[16][108];
    int ti = blockIdx.x, tj = blockIdx.y;
    int i0 = ti * 16, j0 = tj * 16;
    int tid = threadIdx.x;
    // stage e rows (zero-pad cols 100..107)
    for (int idx = tid; idx < 16 * 108; idx += 256) {
        int r = idx / 108, c = idx % 108;
        float v0 = 0.f, v1v = 0.f;
        if (c < 100) {
            v0 = e0[(i0 + r) * 100 + c];
            v1v = e1[(j0 + r) * 100 + c];
        }
        e0s[r][c] = v0;
        e1s[r][c] = v1v;
    }
    __syncthreads();

    int lane = tid & 63;
    int wid = tid >> 6;
    int g = lane >> 4;        // k-subchunk group 0..3
    int jrow = lane & 15;     // A-row = j_local

    f32x4 acc[4][4] = {};     // [f_local][hfrag]

    for (int ks = 0; ks < 8; ++ks) {
        // load B fragments (hi & lo) for 4 h-frags: coalesced 16B, L2-resident
        bf16x8 bh[4], bl[4];
#pragma unroll
        for (int hf = 0; hf < 4; ++hf) {
            int fidx = ((ks * 4 + hf) * 64 + lane) * 8;
            bh[hf] = __builtin_bit_cast(bf16x8, *(const uint4*)(Bhi + fidx));
            bl[hf] = __builtin_bit_cast(bf16x8, *(const uint4*)(Blo + fidx));
        }
        int kbase = ks * 32 + g * 8;
        int term = kbase >> 7;          // 0 = dif, 1 = mul
        int d0 = kbase & 127;
        bool zero = (d0 >= 104);        // pure-pad chunk
        int d0c = zero ? 0 : d0;        // clamp so reads stay in-bounds

#pragma unroll
        for (int fl = 0; fl < 4; ++fl) {
            int f = wid * 4 + fl;       // i_local
            float e0v[8], e1v[8];
            *(float4*)&e0v[0] = *(const float4*)&e0s[f][d0c];
            *(float4*)&e0v[4] = *(const float4*)&e0s[f][d0c + 4];
            *(float4*)&e1v[0] = *(const float4*)&e1s[jrow][d0c];
            *(float4*)&e1v[4] = *(const float4*)&e1s[jrow][d0c + 4];
            bf16x8 ah, al;
#pragma unroll
            for (int e = 0; e < 8; ++e) {
                float x0 = e0v[e], x1 = e1v[e];
                float ft = term ? (x0 * x1) : fabsf(x0 - x1);
                ft = zero ? 0.f : ft;
                unsigned int xb = __float_as_uint(ft);
                float hif = __uint_as_float(xb & 0xFFFF0000u);
                ah[e] = __builtin_bit_cast(__bf16, (unsigned short)(xb >> 16));
                al[e] = (__bf16)(ft - hif);
            }
#pragma unroll
            for (int hf = 0; hf < 4; ++hf) {
                acc[fl][hf] = __builtin_amdgcn_mfma_f32_16x16x32_bf16(ah, bh[hf], acc[fl][hf], 0, 0, 0);
                acc[fl][hf] = __builtin_amdgcn_mfma_f32_16x16x32_bf16(al, bh[hf], acc[fl][hf], 0, 0, 0);
                acc[fl][hf] = __builtin_amdgcn_mfma_f32_16x16x32_bf16(ah, bl[hf], acc[fl][hf], 0, 0, 0);
            }
        }
    }

    // epilogue: D[row=p][col=h]: lane holds p = g*4+r (r=0..3), h = hf*16 + (lane&15)
    int hl = lane & 15;
    int jb = j0 + g * 4;
#pragma unroll
    for (int hf = 0; hf < 4; ++hf) {
        int h = hf * 16 + hl;
        bool ok = h < 50;
        int hc = ok ? h : 0;
        float bnb = b1[hc];
        float sc = g1[hc] * rsqrtf(v1[hc] + EPS);
        float mm = m1[hc];
        float bb = bb1[hc];
#pragma unroll
        for (int fl = 0; fl < 4; ++fl) {
            int i = i0 + wid * 4 + fl;
            f32x4 a = acc[fl][hf];
            float4 o;
            float* op = &o.x;
#pragma unroll
            for (int r = 0; r < 4; ++r) {
                float x = a[r] + bnb;
                x = elu_f(x);
                x = (x - mm) * sc + bb;
                x = elu_f(x);
                op[r] = x;
            }
            if (ok) {
                *(float4*)&Bmap[(size_t)h * 640000 + (size_t)i * 800 + jb] = o;
            }
        }
    }
}

// ---------------- Kernel 3: 7x7 conv over 50 channels + b2 + bn2 ----------------
__global__ __launch_bounds__(256) void kconv(const float* __restrict__ Bmap,
                                             const float* __restrict__ W2,
                                             const float* __restrict__ b2,
                                             const float* __restrict__ g2,
                                             const float* __restrict__ bb2,
                                             const float* __restrict__ m2,
                                             const float* __restrict__ v2,
                                             float* __restrict__ C) {
    __shared__ float tile[38][40];
    __shared__ float w2s[50][49];
    int ti = blockIdx.y, tj = blockIdx.x;
    int tid = threadIdx.x;
    for (int idx = tid; idx < 2450; idx += 256) w2s[idx / 49][idx % 49] = W2[idx];
    int ly = tid >> 3;
    int lx = tid & 7;
    int i0 = ti * 32 + ly;
    int j0 = tj * 32 + lx * 4;
    float acc[4] = {0.f, 0.f, 0.f, 0.f};
    for (int h = 0; h < 50; h++) {
        __syncthreads();
        const float* plane = Bmap + (size_t)h * 640000;
        for (int idx = tid; idx < 38 * 38; idx += 256) {
            int r = idx / 38, c = idx % 38;
            int gy = ti * 32 - 3 + r;
            int gx = tj * 32 - 3 + c;
            float val = 0.f;
            if (gy >= 0 && gy < 800 && gx >= 0 && gx < 800) val = plane[gy * 800 + gx];
            tile[r][c] = val;
        }
        __syncthreads();
#pragma unroll
        for (int di = 0; di < 7; di++) {
            const float* trow = &tile[ly + di][lx * 4];
            float4 ra = *(const float4*)(trow);
            float4 rb = *(const float4*)(trow + 4);
            float rv[10] = {ra.x, ra.y, ra.z, ra.w, rb.x, rb.y, rb.z, rb.w,
                            trow[8], trow[9]};
#pragma unroll
            for (int dj = 0; dj < 7; dj++) {
                float w = w2s[h][di * 7 + dj];
                acc[0] = fmaf(rv[dj + 0], w, acc[0]);
                acc[1] = fmaf(rv[dj + 1], w, acc[1]);
                acc[2] = fmaf(rv[dj + 2], w, acc[2]);
                acc[3] = fmaf(rv[dj + 3], w, acc[3]);
            }
        }
    }
    float s2 = g2[0] * rsqrtf(v2[0] + EPS);
    float t2 = bb2[0] - m2[0] * s2;
    float bias = b2[0];
    float4 out;
    out.x = (acc[0] + bias) * s2 + t2;
    out.y = (acc[1] + bias) * s2 + t2;
    out.z = (acc[2] + bias) * s2 + t2;
    out.w = (acc[3] + bias) * s2 + t2;
    *(float4*)&C[(size_t)i0 * 800 + j0] = out;
}

// ---------------- Kernel 4: 9x9/9 maxpool with pad 4 -> yhat (89x89) ----------------
__global__ __launch_bounds__(256) void kpool(const float* __restrict__ C,
                                             float* __restrict__ yhat) {
    int idx = blockIdx.x * 256 + threadIdx.x;
    if (idx >= 89 * 89) return;
    int oy = idx / 89, ox = idx % 89;
    float mx = -INFINITY;
    int y0 = oy * 9 - 4, x0 = ox * 9 - 4;
    for (int dy = 0; dy < 9; dy++) {
        int y = y0 + dy;
        if (y < 0 || y >= 800) continue;
        for (int dx = 0; dx < 9; dx++) {
            int x = x0 + dx;
            if (x < 0 || x >= 800) continue;
            mx = fmaxf(mx, C[y * 800 + x]);
        }
    }
    yhat[idx] = mx;
}

// ---------------- Kernel 5: mean/var -> Q -> phat -> gelu ----------------
__global__ __launch_bounds__(256) void kfinal(const float* __restrict__ yhat,
                                              const float* __restrict__ gamma,
                                              float* __restrict__ out) {
    const int N = 89 * 89;
    __shared__ float sA[4], sB[4];
    int tid = threadIdx.x;
    int wid = tid >> 6, lane = tid & 63;
    float s = 0.f, ss = 0.f;
    for (int i = tid; i < N; i += 256) {
        float y = yhat[i];
        s += y;
        ss = fmaf(y, y, ss);
    }
    for (int off = 32; off; off >>= 1) {
        s += __shfl_down(s, off);
        ss += __shfl_down(ss, off);
    }
    if (lane == 0) { sA[wid] = s; sB[wid] = ss; }
    __syncthreads();
    float S = sA[0] + sA[1] + sA[2] + sA[3];
    float SS = sB[0] + sB[1] + sB[2] + sB[3];
    float mu = S / (float)N;
    float var = (SS - S * S / (float)N) / (float)(N - 1);
    float thr = mu + gamma[0] * var;
    __syncthreads();
    float q = 0.f, c = 0.f;
    for (int i = tid; i < N; i += 256) {
        float d = yhat[i] - thr;
        if (d > 0.f) { q += d; c += 1.f; }
    }
    for (int off = 32; off; off >>= 1) {
        q += __shfl_down(q, off);
        c += __shfl_down(c, off);
    }
    if (lane == 0) { sA[wid] = q; sB[wid] = c; }
    __syncthreads();
    if (tid == 0) {
        float Q = sA[0] + sA[1] + sA[2] + sA[3];
        float Cnt = sB[0] + sB[1] + sB[2] + sB[3];
        float phat = Q / (Cnt + 1.f);
        out[0] = 0.5f * phat * (1.f + erff(phat * 0.70710678118654752f));
    }
}

extern "C" void kernel_launch(void* const* d_in, const int* in_sizes, int n_in,
                              void* d_out, int out_size, void* d_ws, size_t ws_size,
                              hipStream_t stream) {
    const float* z0   = (const float*)d_in[0];
    const float* z1   = (const float*)d_in[1];
    const float* Wemb = (const float*)d_in[2];
    const float* bemb = (const float*)d_in[3];
    const float* W1   = (const float*)d_in[4];
    const float* b1   = (const float*)d_in[5];
    const float* bn1g = (const float*)d_in[6];
    const float* bn1b = (const float*)d_in[7];
    const float* bn1m = (const float*)d_in[8];
    const float* bn1v = (const float*)d_in[9];
    const float* W2   = (const float*)d_in[10];
    const float* b2   = (const float*)d_in[11];
    const float* bn2g = (const float*)d_in[12];
    const float* bn2b = (const float*)d_in[13];
    const float* bn2m = (const float*)d_in[14];
    const float* bn2v = (const float*)d_in[15];
    const float* gam  = (const float*)d_in[16];

    float* ws   = (float*)d_ws;
    float* e0   = ws;                       // 80000
    float* e1   = ws + 80000;               // 80000
    float* Bmap = ws + 160000;              // 32,000,000
    float* Cbuf = ws + 160000 + 32000000;   // 640,000 (prep scratch lives here pre-conv)
    float* yhat = Cbuf + 640000;            // 7921
    float* out  = (float*)d_out;

    // W1 fragment pack (hi/lo) carved from the C region (dead until kconv runs)
    unsigned short* Bhi = (unsigned short*)Cbuf;   // 16384 ushorts = 32KB
    unsigned short* Blo = Bhi + 16384;             // 32KB

    kembed<<<200, 256, 0, stream>>>(z0, z1, Wemb, bemb, e0, e1);
    kprepW<<<64, 256, 0, stream>>>(W1, Bhi, Blo);
    dim3 gi(50, 50);
    kinter<<<gi, 256, 0, stream>>>(e0, e1, Bhi, Blo, b1, bn1g, bn1b, bn1m, bn1v, Bmap);
    dim3 gc(25, 25);
    kconv<<<gc, 256, 0, stream>>>(Bmap, W2, b2, bn2g, bn2b, bn2m, bn2v, Cbuf);
    kpool<<<(89 * 89 + 255) / 256, 256, 0, stream>>>(Cbuf, yhat);
    kfinal<<<1, 256, 0, stream>>>(yhat, gam, out);
}

// Round 3
// 324.862 us; speedup vs baseline: 1.9206x; 1.2092x over previous
//
#include <hip/hip_runtime.h>
#include <hip/hip_bf16.h>
#include <math.h>

#define EPS 1e-5f

typedef __bf16 bf16x8 __attribute__((ext_vector_type(8)));
typedef float f32x4 __attribute__((ext_vector_type(4)));

__device__ __forceinline__ float elu_f(float x) {
    return x > 0.f ? x : __expf(x) - 1.f;
}

// ---------------- Kernel 1: e = elu(z @ W_emb^T + b_emb) ----------------
__global__ __launch_bounds__(256) void kembed(const float* __restrict__ z0,
                                              const float* __restrict__ z1,
                                              const float* __restrict__ Wemb,
                                              const float* __restrict__ bemb,
                                              float* __restrict__ e0,
                                              float* __restrict__ e1) {
    __shared__ float4 zs4[2048];  // 8 rows x 1024 floats
    int src = blockIdx.x & 1;
    int rowbase = (blockIdx.x >> 1) * 8;
    const float* z = src ? z1 : z0;
    float* e = src ? e1 : e0;
    const float4* zrow4 = reinterpret_cast<const float4*>(z + rowbase * 1024);
    for (int idx = threadIdx.x; idx < 2048; idx += 256) zs4[idx] = zrow4[idx];
    __syncthreads();
    int t = threadIdx.x;
    if (t < 200) {
        int d = t % 100;
        int half = t / 100;
        const float4* w4 = reinterpret_cast<const float4*>(Wemb + d * 1024);
        float acc[4] = {0.f, 0.f, 0.f, 0.f};
        for (int k = 0; k < 256; k++) {
            float4 w = w4[k];
#pragma unroll
            for (int r = 0; r < 4; r++) {
                float4 zv = zs4[(half * 4 + r) * 256 + k];
                acc[r] = fmaf(w.x, zv.x, acc[r]);
                acc[r] = fmaf(w.y, zv.y, acc[r]);
                acc[r] = fmaf(w.z, zv.z, acc[r]);
                acc[r] = fmaf(w.w, zv.w, acc[r]);
            }
        }
        float be = bemb[d];
#pragma unroll
        for (int r = 0; r < 4; r++) {
            e[(rowbase + half * 4 + r) * 100 + d] = elu_f(acc[r] + be);
        }
    }
}

// ---------------- Prep: pack W1 (split hi/lo bf16) into B-fragment order ----------------
__global__ __launch_bounds__(256) void kprepW(const float* __restrict__ W1,
                                              unsigned short* __restrict__ Bhi,
                                              unsigned short* __restrict__ Blo) {
    int idx = blockIdx.x * 256 + threadIdx.x;
    if (idx >= 16384) return;
    int i = idx & 7;
    int lane = (idx >> 3) & 63;
    int hf = (idx >> 9) & 3;
    int ks = idx >> 11;
    int h = hf * 16 + (lane & 15);
    int k = ks * 32 + (lane >> 4) * 8 + i;
    int term = k >> 7;
    int d = k & 127;
    float val = (d < 100 && h < 50) ? W1[h * 200 + term * 100 + d] : 0.f;
    unsigned int vb = __float_as_uint(val);
    float hif = __uint_as_float(vb & 0xFFFF0000u);
    Bhi[idx] = (unsigned short)(vb >> 16);
    float lo = val - hif;
    Blo[idx] = __builtin_bit_cast(unsigned short, (__bf16)lo);
}

// ---------------- Kernel 2: interaction GEMM via MFMA (split bf16) ----------------
// Bmap now stored as bf16 planes (50 x 800 x 800).
__global__ __launch_bounds__(256) void kinter(const float* __restrict__ e0,
                                              const float* __restrict__ e1,
                                              const unsigned short* __restrict__ Bhi,
                                              const unsigned short* __restrict__ Blo,
                                              const float* __restrict__ b1,
                                              const float* __restrict__ g1,
                                              const float* __restrict__ bb1,
                                              const float* __restrict__ m1,
                                              const float* __restrict__ v1,
                                              __hip_bfloat16* __restrict__ Bmap) {
    __shared__ float e0s[16][108];
    __shared__ float e1s[16][108];
    int ti = blockIdx.x, tj = blockIdx.y;
    int i0 = ti * 16, j0 = tj * 16;
    int tid = threadIdx.x;
    for (int idx = tid; idx < 16 * 108; idx += 256) {
        int r = idx / 108, c = idx % 108;
        float v0 = 0.f, v1v = 0.f;
        if (c < 100) {
            v0 = e0[(i0 + r) * 100 + c];
            v1v = e1[(j0 + r) * 100 + c];
        }
        e0s[r][c] = v0;
        e1s[r][c] = v1v;
    }
    __syncthreads();

    int lane = tid & 63;
    int wid = tid >> 6;
    int g = lane >> 4;
    int jrow = lane & 15;

    f32x4 acc[4][4] = {};

    for (int ks = 0; ks < 8; ++ks) {
        bf16x8 bh[4], bl[4];
#pragma unroll
        for (int hf = 0; hf < 4; ++hf) {
            int fidx = ((ks * 4 + hf) * 64 + lane) * 8;
            bh[hf] = __builtin_bit_cast(bf16x8, *(const uint4*)(Bhi + fidx));
            bl[hf] = __builtin_bit_cast(bf16x8, *(const uint4*)(Blo + fidx));
        }
        int kbase = ks * 32 + g * 8;
        int term = kbase >> 7;
        int d0 = kbase & 127;
        bool zero = (d0 >= 104);
        int d0c = zero ? 0 : d0;

#pragma unroll
        for (int fl = 0; fl < 4; ++fl) {
            int f = wid * 4 + fl;
            float e0v[8], e1v[8];
            *(float4*)&e0v[0] = *(const float4*)&e0s[f][d0c];
            *(float4*)&e0v[4] = *(const float4*)&e0s[f][d0c + 4];
            *(float4*)&e1v[0] = *(const float4*)&e1s[jrow][d0c];
            *(float4*)&e1v[4] = *(const float4*)&e1s[jrow][d0c + 4];
            bf16x8 ah, al;
#pragma unroll
            for (int e = 0; e < 8; ++e) {
                float x0 = e0v[e], x1 = e1v[e];
                float ft = term ? (x0 * x1) : fabsf(x0 - x1);
                ft = zero ? 0.f : ft;
                unsigned int xb = __float_as_uint(ft);
                float hif = __uint_as_float(xb & 0xFFFF0000u);
                ah[e] = __builtin_bit_cast(__bf16, (unsigned short)(xb >> 16));
                al[e] = (__bf16)(ft - hif);
            }
#pragma unroll
            for (int hf = 0; hf < 4; ++hf) {
                acc[fl][hf] = __builtin_amdgcn_mfma_f32_16x16x32_bf16(ah, bh[hf], acc[fl][hf], 0, 0, 0);
                acc[fl][hf] = __builtin_amdgcn_mfma_f32_16x16x32_bf16(al, bh[hf], acc[fl][hf], 0, 0, 0);
                acc[fl][hf] = __builtin_amdgcn_mfma_f32_16x16x32_bf16(ah, bl[hf], acc[fl][hf], 0, 0, 0);
            }
        }
    }

    int hl = lane & 15;
    int jb = j0 + g * 4;
#pragma unroll
    for (int hf = 0; hf < 4; ++hf) {
        int h = hf * 16 + hl;
        bool ok = h < 50;
        int hc = ok ? h : 0;
        float bnb = b1[hc];
        float sc = g1[hc] * rsqrtf(v1[hc] + EPS);
        float mm = m1[hc];
        float bb = bb1[hc];
#pragma unroll
        for (int fl = 0; fl < 4; ++fl) {
            int i = i0 + wid * 4 + fl;
            f32x4 a = acc[fl][hf];
            unsigned short o[4];
#pragma unroll
            for (int r = 0; r < 4; ++r) {
                float x = a[r] + bnb;
                x = elu_f(x);
                x = (x - mm) * sc + bb;
                x = elu_f(x);
                o[r] = __builtin_bit_cast(unsigned short, (__bf16)x);
            }
            if (ok) {
                *(ushort4*)&Bmap[(size_t)h * 640000 + (size_t)i * 800 + jb] =
                    *(ushort4*)o;
            }
        }
    }
}

// ---------------- Kernel 3: 7x7 conv, channel-split partials ----------------
// grid (25,25,5); block 256. Each z-block: 10 channels -> partial sum plane.
__global__ __launch_bounds__(256) void kconv(const __hip_bfloat16* __restrict__ Bmap,
                                             const float* __restrict__ W2,
                                             float* __restrict__ Cpart) {
    __shared__ float tile[38][40];
    __shared__ float w2s[10][49];
    int ti = blockIdx.y, tj = blockIdx.x, zc = blockIdx.z;
    int h0 = zc * 10;
    int tid = threadIdx.x;
    for (int idx = tid; idx < 490; idx += 256) w2s[idx / 49][idx % 49] = W2[h0 * 49 + idx];
    int ly = tid >> 3;
    int lx = tid & 7;
    int i0 = ti * 32 + ly;
    int j0 = tj * 32 + lx * 4;
    float acc[4] = {0.f, 0.f, 0.f, 0.f};
    for (int hh = 0; hh < 10; hh++) {
        __syncthreads();
        const __hip_bfloat16* plane = Bmap + (size_t)(h0 + hh) * 640000;
        for (int idx = tid; idx < 38 * 38; idx += 256) {
            int r = idx / 38, c = idx % 38;
            int gy = ti * 32 - 3 + r;
            int gx = tj * 32 - 3 + c;
            float val = 0.f;
            if (gy >= 0 && gy < 800 && gx >= 0 && gx < 800)
                val = __bfloat162float(plane[gy * 800 + gx]);
            tile[r][c] = val;
        }
        __syncthreads();
#pragma unroll
        for (int di = 0; di < 7; di++) {
            const float* trow = &tile[ly + di][lx * 4];
            float4 ra = *(const float4*)(trow);
            float4 rb = *(const float4*)(trow + 4);
            float rv[10] = {ra.x, ra.y, ra.z, ra.w, rb.x, rb.y, rb.z, rb.w,
                            trow[8], trow[9]};
#pragma unroll
            for (int dj = 0; dj < 7; dj++) {
                float w = w2s[hh][di * 7 + dj];
                acc[0] = fmaf(rv[dj + 0], w, acc[0]);
                acc[1] = fmaf(rv[dj + 1], w, acc[1]);
                acc[2] = fmaf(rv[dj + 2], w, acc[2]);
                acc[3] = fmaf(rv[dj + 3], w, acc[3]);
            }
        }
    }
    *(float4*)&Cpart[(size_t)zc * 640000 + (size_t)i0 * 800 + j0] =
        *(float4*)acc;
}

// ---------------- Kernel 3b: reduce partials + bias + bn2 ----------------
__global__ __launch_bounds__(256) void kreduce(const float* __restrict__ Cpart,
                                               const float* __restrict__ b2,
                                               const float* __restrict__ g2,
                                               const float* __restrict__ bb2,
                                               const float* __restrict__ m2,
                                               const float* __restrict__ v2,
                                               float* __restrict__ C) {
    int idx = blockIdx.x * 256 + threadIdx.x;
    if (idx >= 160000) return;  // float4 granularity: 640000/4
    float s2 = g2[0] * rsqrtf(v2[0] + EPS);
    float t2 = bb2[0] - m2[0] * s2;
    float bias = b2[0];
    float4 s = ((const float4*)Cpart)[idx];
#pragma unroll
    for (int z = 1; z < 5; z++) {
        float4 p = ((const float4*)(Cpart + (size_t)z * 640000))[idx];
        s.x += p.x; s.y += p.y; s.z += p.z; s.w += p.w;
    }
    s.x = (s.x + bias) * s2 + t2;
    s.y = (s.y + bias) * s2 + t2;
    s.z = (s.z + bias) * s2 + t2;
    s.w = (s.w + bias) * s2 + t2;
    ((float4*)C)[idx] = s;
}

// ---------------- Kernel 4: 9x9/9 maxpool with pad 4 -> yhat (89x89) ----------------
__global__ __launch_bounds__(256) void kpool(const float* __restrict__ C,
                                             float* __restrict__ yhat) {
    int idx = blockIdx.x * 256 + threadIdx.x;
    if (idx >= 89 * 89) return;
    int oy = idx / 89, ox = idx % 89;
    float mx = -INFINITY;
    int y0 = oy * 9 - 4, x0 = ox * 9 - 4;
    for (int dy = 0; dy < 9; dy++) {
        int y = y0 + dy;
        if (y < 0 || y >= 800) continue;
        for (int dx = 0; dx < 9; dx++) {
            int x = x0 + dx;
            if (x < 0 || x >= 800) continue;
            mx = fmaxf(mx, C[y * 800 + x]);
        }
    }
    yhat[idx] = mx;
}

// ---------------- Kernel 5: mean/var -> Q -> phat -> gelu ----------------
__global__ __launch_bounds__(256) void kfinal(const float* __restrict__ yhat,
                                              const float* __restrict__ gamma,
                                              float* __restrict__ out) {
    const int N = 89 * 89;
    __shared__ float sA[4], sB[4];
    int tid = threadIdx.x;
    int wid = tid >> 6, lane = tid & 63;
    float s = 0.f, ss = 0.f;
    for (int i = tid; i < N; i += 256) {
        float y = yhat[i];
        s += y;
        ss = fmaf(y, y, ss);
    }
    for (int off = 32; off; off >>= 1) {
        s += __shfl_down(s, off);
        ss += __shfl_down(ss, off);
    }
    if (lane == 0) { sA[wid] = s; sB[wid] = ss; }
    __syncthreads();
    float S = sA[0] + sA[1] + sA[2] + sA[3];
    float SS = sB[0] + sB[1] + sB[2] + sB[3];
    float mu = S / (float)N;
    float var = (SS - S * S / (float)N) / (float)(N - 1);
    float thr = mu + gamma[0] * var;
    __syncthreads();
    float q = 0.f, c = 0.f;
    for (int i = tid; i < N; i += 256) {
        float d = yhat[i] - thr;
        if (d > 0.f) { q += d; c += 1.f; }
    }
    for (int off = 32; off; off >>= 1) {
        q += __shfl_down(q, off);
        c += __shfl_down(c, off);
    }
    if (lane == 0) { sA[wid] = q; sB[wid] = c; }
    __syncthreads();
    if (tid == 0) {
        float Q = sA[0] + sA[1] + sA[2] + sA[3];
        float Cnt = sB[0] + sB[1] + sB[2] + sB[3];
        float phat = Q / (Cnt + 1.f);
        out[0] = 0.5f * phat * (1.f + erff(phat * 0.70710678118654752f));
    }
}

extern "C" void kernel_launch(void* const* d_in, const int* in_sizes, int n_in,
                              void* d_out, int out_size, void* d_ws, size_t ws_size,
                              hipStream_t stream) {
    const float* z0   = (const float*)d_in[0];
    const float* z1   = (const float*)d_in[1];
    const float* Wemb = (const float*)d_in[2];
    const float* bemb = (const float*)d_in[3];
    const float* W1   = (const float*)d_in[4];
    const float* b1   = (const float*)d_in[5];
    const float* bn1g = (const float*)d_in[6];
    const float* bn1b = (const float*)d_in[7];
    const float* bn1m = (const float*)d_in[8];
    const float* bn1v = (const float*)d_in[9];
    const float* W2   = (const float*)d_in[10];
    const float* b2   = (const float*)d_in[11];
    const float* bn2g = (const float*)d_in[12];
    const float* bn2b = (const float*)d_in[13];
    const float* bn2m = (const float*)d_in[14];
    const float* bn2v = (const float*)d_in[15];
    const float* gam  = (const float*)d_in[16];

    float* ws   = (float*)d_ws;
    float* e0   = ws;                                   // 80,000 f32
    float* e1   = ws + 80000;                           // 80,000 f32
    __hip_bfloat16* Bmap = (__hip_bfloat16*)(ws + 160000);  // 32,000,000 bf16 (=16,000,000 f32 slots)
    float* Cpart = ws + 160000 + 16000000;              // 5 x 640,000 f32
    float* Cbuf  = Cpart + 3200000;                     // 640,000 f32
    float* yhat  = Cbuf + 640000;                       // 7,921 f32
    unsigned short* Bhi = (unsigned short*)(yhat + 8000);  // 16,384 u16
    unsigned short* Blo = Bhi + 16384;                     // 16,384 u16
    float* out  = (float*)d_out;

    kembed<<<200, 256, 0, stream>>>(z0, z1, Wemb, bemb, e0, e1);
    kprepW<<<64, 256, 0, stream>>>(W1, Bhi, Blo);
    dim3 gi(50, 50);
    kinter<<<gi, 256, 0, stream>>>(e0, e1, Bhi, Blo, b1, bn1g, bn1b, bn1m, bn1v, Bmap);
    dim3 gc(25, 25, 5);
    kconv<<<gc, 256, 0, stream>>>(Bmap, W2, Cpart);
    kreduce<<<(160000 + 255) / 256, 256, 0, stream>>>(Cpart, b2, bn2g, bn2b, bn2m, bn2v, Cbuf);
    kpool<<<(89 * 89 + 255) / 256, 256, 0, stream>>>(Cbuf, yhat);
    kfinal<<<1, 256, 0, stream>>>(yhat, gam, out);
}

// Round 4
// 261.908 us; speedup vs baseline: 2.3823x; 1.2404x over previous
//
#include <hip/hip_runtime.h>
#include <hip/hip_bf16.h>
#include <math.h>

#define EPS 1e-5f
#define ST 816                 // padded Bmap row stride (elems)
#define PLANE (816 * 808)      // padded plane elems (rows 0..807)

typedef __bf16 bf16x8 __attribute__((ext_vector_type(8)));
typedef float f32x4 __attribute__((ext_vector_type(4)));

__device__ __forceinline__ float elu_f(float x) {
    return x > 0.f ? x : __expf(x) - 1.f;
}

// ---------------- Kernel 1: e = elu(z @ W_emb^T + b_emb) ----------------
__global__ __launch_bounds__(256) void kembed(const float* __restrict__ z0,
                                              const float* __restrict__ z1,
                                              const float* __restrict__ Wemb,
                                              const float* __restrict__ bemb,
                                              float* __restrict__ e0,
                                              float* __restrict__ e1) {
    __shared__ float4 zs4[2048];  // 8 rows x 1024 floats
    int src = blockIdx.x & 1;
    int rowbase = (blockIdx.x >> 1) * 8;
    const float* z = src ? z1 : z0;
    float* e = src ? e1 : e0;
    const float4* zrow4 = reinterpret_cast<const float4*>(z + rowbase * 1024);
    for (int idx = threadIdx.x; idx < 2048; idx += 256) zs4[idx] = zrow4[idx];
    __syncthreads();
    int t = threadIdx.x;
    if (t < 200) {
        int d = t % 100;
        int half = t / 100;
        const float4* w4 = reinterpret_cast<const float4*>(Wemb + d * 1024);
        float acc[4] = {0.f, 0.f, 0.f, 0.f};
        for (int k = 0; k < 256; k++) {
            float4 w = w4[k];
#pragma unroll
            for (int r = 0; r < 4; r++) {
                float4 zv = zs4[(half * 4 + r) * 256 + k];
                acc[r] = fmaf(w.x, zv.x, acc[r]);
                acc[r] = fmaf(w.y, zv.y, acc[r]);
                acc[r] = fmaf(w.z, zv.z, acc[r]);
                acc[r] = fmaf(w.w, zv.w, acc[r]);
            }
        }
        float be = bemb[d];
#pragma unroll
        for (int r = 0; r < 4; r++) {
            e[(rowbase + half * 4 + r) * 100 + d] = elu_f(acc[r] + be);
        }
    }
}

// ---------------- Prep: pack W1 (split hi/lo bf16) into B-fragment order ----------------
__global__ __launch_bounds__(256) void kprepW(const float* __restrict__ W1,
                                              unsigned short* __restrict__ Bhi,
                                              unsigned short* __restrict__ Blo) {
    int idx = blockIdx.x * 256 + threadIdx.x;
    if (idx >= 16384) return;
    int i = idx & 7;
    int lane = (idx >> 3) & 63;
    int hf = (idx >> 9) & 3;
    int ks = idx >> 11;
    int h = hf * 16 + (lane & 15);
    int k = ks * 32 + (lane >> 4) * 8 + i;
    int term = k >> 7;
    int d = k & 127;
    float val = (d < 100 && h < 50) ? W1[h * 200 + term * 100 + d] : 0.f;
    unsigned int vb = __float_as_uint(val);
    float hif = __uint_as_float(vb & 0xFFFF0000u);
    Bhi[idx] = (unsigned short)(vb >> 16);
    float lo = val - hif;
    Blo[idx] = __builtin_bit_cast(unsigned short, (__bf16)lo);
}

// ---------------- kzero: zero the halo borders of padded Bmap ----------------
// Per plane: rows {0,1,2,803,804,805} full width (6*816=4896) and
// cols {0..7, 808..815} for rows 3..802 (800*16=12800).
__global__ __launch_bounds__(256) void kzero(unsigned short* __restrict__ Bmap) {
    const int per = 4896 + 12800;
    int idx = blockIdx.x * 256 + threadIdx.x;
    if (idx >= 50 * per) return;
    int h = idx / per, q = idx % per;
    int row, col;
    if (q < 4896) {
        int rr = q / 816;
        col = q - rr * 816;
        row = rr < 3 ? rr : 800 + rr;
    } else {
        int q2 = q - 4896;
        row = 3 + (q2 >> 4);
        int m = q2 & 15;
        col = m < 8 ? m : 800 + m;
    }
    Bmap[(size_t)h * PLANE + (size_t)row * ST + col] = 0;
}

// ---------------- Kernel 2: interaction GEMM via MFMA (split bf16) ----------------
// Bmap stored as bf16 padded planes: elem (h, i, j) at h*PLANE + (i+3)*ST + (j+8).
__global__ __launch_bounds__(256) void kinter(const float* __restrict__ e0,
                                              const float* __restrict__ e1,
                                              const unsigned short* __restrict__ Bhi,
                                              const unsigned short* __restrict__ Blo,
                                              const float* __restrict__ b1,
                                              const float* __restrict__ g1,
                                              const float* __restrict__ bb1,
                                              const float* __restrict__ m1,
                                              const float* __restrict__ v1,
                                              __hip_bfloat16* __restrict__ Bmap) {
    __shared__ float e0s[16][108];
    __shared__ float e1s[16][108];
    int ti = blockIdx.x, tj = blockIdx.y;
    int i0 = ti * 16, j0 = tj * 16;
    int tid = threadIdx.x;
    for (int idx = tid; idx < 16 * 108; idx += 256) {
        int r = idx / 108, c = idx % 108;
        float v0 = 0.f, v1v = 0.f;
        if (c < 100) {
            v0 = e0[(i0 + r) * 100 + c];
            v1v = e1[(j0 + r) * 100 + c];
        }
        e0s[r][c] = v0;
        e1s[r][c] = v1v;
    }
    __syncthreads();

    int lane = tid & 63;
    int wid = tid >> 6;
    int g = lane >> 4;
    int jrow = lane & 15;

    f32x4 acc[4][4] = {};

    for (int ks = 0; ks < 8; ++ks) {
        bf16x8 bh[4], bl[4];
#pragma unroll
        for (int hf = 0; hf < 4; ++hf) {
            int fidx = ((ks * 4 + hf) * 64 + lane) * 8;
            bh[hf] = __builtin_bit_cast(bf16x8, *(const uint4*)(Bhi + fidx));
            bl[hf] = __builtin_bit_cast(bf16x8, *(const uint4*)(Blo + fidx));
        }
        int kbase = ks * 32 + g * 8;
        int term = kbase >> 7;
        int d0 = kbase & 127;
        bool zero = (d0 >= 104);
        int d0c = zero ? 0 : d0;

#pragma unroll
        for (int fl = 0; fl < 4; ++fl) {
            int f = wid * 4 + fl;
            float e0v[8], e1v[8];
            *(float4*)&e0v[0] = *(const float4*)&e0s[f][d0c];
            *(float4*)&e0v[4] = *(const float4*)&e0s[f][d0c + 4];
            *(float4*)&e1v[0] = *(const float4*)&e1s[jrow][d0c];
            *(float4*)&e1v[4] = *(const float4*)&e1s[jrow][d0c + 4];
            bf16x8 ah, al;
#pragma unroll
            for (int e = 0; e < 8; ++e) {
                float x0 = e0v[e], x1 = e1v[e];
                float ft = term ? (x0 * x1) : fabsf(x0 - x1);
                ft = zero ? 0.f : ft;
                unsigned int xb = __float_as_uint(ft);
                float hif = __uint_as_float(xb & 0xFFFF0000u);
                ah[e] = __builtin_bit_cast(__bf16, (unsigned short)(xb >> 16));
                al[e] = (__bf16)(ft - hif);
            }
#pragma unroll
            for (int hf = 0; hf < 4; ++hf) {
                acc[fl][hf] = __builtin_amdgcn_mfma_f32_16x16x32_bf16(ah, bh[hf], acc[fl][hf], 0, 0, 0);
                acc[fl][hf] = __builtin_amdgcn_mfma_f32_16x16x32_bf16(al, bh[hf], acc[fl][hf], 0, 0, 0);
                acc[fl][hf] = __builtin_amdgcn_mfma_f32_16x16x32_bf16(ah, bl[hf], acc[fl][hf], 0, 0, 0);
            }
        }
    }

    int hl = lane & 15;
    int jb = j0 + g * 4;
#pragma unroll
    for (int hf = 0; hf < 4; ++hf) {
        int h = hf * 16 + hl;
        bool ok = h < 50;
        int hc = ok ? h : 0;
        float bnb = b1[hc];
        float sc = g1[hc] * rsqrtf(v1[hc] + EPS);
        float mm = m1[hc];
        float bb = bb1[hc];
#pragma unroll
        for (int fl = 0; fl < 4; ++fl) {
            int i = i0 + wid * 4 + fl;
            f32x4 a = acc[fl][hf];
            unsigned short o[4];
#pragma unroll
            for (int r = 0; r < 4; ++r) {
                float x = a[r] + bnb;
                x = elu_f(x);
                x = (x - mm) * sc + bb;
                x = elu_f(x);
                o[r] = __builtin_bit_cast(unsigned short, (__bf16)x);
            }
            if (ok) {
                *(ushort4*)&Bmap[(size_t)h * PLANE + (size_t)(i + 3) * ST + (jb + 8)] =
                    *(ushort4*)o;
            }
        }
    }
}

// ---------------- Kernel 3: 7x7 conv, 64x64 tile, 4x4 outputs/thread ----------------
// grid (13,13,10); block 256. z-chunk = 5 channels -> partial plane.
__global__ __launch_bounds__(256) void kconv(const __hip_bfloat16* __restrict__ Bmap,
                                             const float* __restrict__ W2,
                                             float* __restrict__ Cpart) {
    __shared__ float tile[70][80];
    __shared__ float w2s[49];
    int bx = blockIdx.x, by = blockIdx.y, zc = blockIdx.z;
    int h0 = zc * 5;
    int tid = threadIdx.x;
    int ly = tid >> 4, lx = tid & 15;     // 16x16 threads, 4x4 outputs each
    float acc[4][4] = {};
    for (int hh = 0; hh < 5; ++hh) {
        int h = h0 + hh;
        __syncthreads();
        const __hip_bfloat16* plane = Bmap + (size_t)h * PLANE;
        // stage 70 rows x 80 cols (10 x uint4 of 8 bf16 per row), aligned, no branches
        for (int u = tid; u < 700; u += 256) {
            int r = u / 10, k = u - r * 10;
            uint4 v = *reinterpret_cast<const uint4*>(
                plane + (size_t)(64 * by + r) * ST + 64 * bx + 8 * k);
            float f[8];
            f[0] = __uint_as_float(v.x << 16);
            f[1] = __uint_as_float(v.x & 0xFFFF0000u);
            f[2] = __uint_as_float(v.y << 16);
            f[3] = __uint_as_float(v.y & 0xFFFF0000u);
            f[4] = __uint_as_float(v.z << 16);
            f[5] = __uint_as_float(v.z & 0xFFFF0000u);
            f[6] = __uint_as_float(v.w << 16);
            f[7] = __uint_as_float(v.w & 0xFFFF0000u);
            *(float4*)&tile[r][8 * k] = *(float4*)&f[0];
            *(float4*)&tile[r][8 * k + 4] = *(float4*)&f[4];
        }
        if (tid < 49) w2s[tid] = W2[h * 49 + tid];
        __syncthreads();
        float wr[49];
#pragma unroll
        for (int q = 0; q < 49; ++q) wr[q] = w2s[q];
#pragma unroll
        for (int r = 0; r < 10; ++r) {
            float w[12];
            *(float4*)&w[0] = *(const float4*)&tile[4 * ly + r][4 * lx + 4];
            *(float4*)&w[4] = *(const float4*)&tile[4 * ly + r][4 * lx + 8];
            *(float4*)&w[8] = *(const float4*)&tile[4 * ly + r][4 * lx + 12];
#pragma unroll
            for (int rr = 0; rr < 4; ++rr) {
                int di = r - rr;
                if (di < 0 || di > 6) continue;
#pragma unroll
                for (int dj = 0; dj < 7; ++dj) {
                    float wt = wr[di * 7 + dj];
#pragma unroll
                    for (int cc = 0; cc < 4; ++cc)
                        acc[rr][cc] = fmaf(w[cc + dj + 1], wt, acc[rr][cc]);
                }
            }
        }
    }
    int j = 64 * bx + 4 * lx;
    if (j < 800) {
#pragma unroll
        for (int rr = 0; rr < 4; ++rr) {
            int i = 64 * by + 4 * ly + rr;
            if (i < 800)
                *(float4*)&Cpart[(size_t)zc * 640000 + (size_t)i * 800 + j] =
                    *(float4*)acc[rr];
        }
    }
}

// ---------------- Kernel 3b: reduce partials + bias + bn2 ----------------
__global__ __launch_bounds__(256) void kreduce(const float* __restrict__ Cpart,
                                               const float* __restrict__ b2,
                                               const float* __restrict__ g2,
                                               const float* __restrict__ bb2,
                                               const float* __restrict__ m2,
                                               const float* __restrict__ v2,
                                               float* __restrict__ C) {
    int idx = blockIdx.x * 256 + threadIdx.x;
    if (idx >= 160000) return;
    float s2 = g2[0] * rsqrtf(v2[0] + EPS);
    float t2 = bb2[0] - m2[0] * s2;
    float bias = b2[0];
    float4 s = ((const float4*)Cpart)[idx];
#pragma unroll
    for (int z = 1; z < 10; z++) {
        float4 p = ((const float4*)(Cpart + (size_t)z * 640000))[idx];
        s.x += p.x; s.y += p.y; s.z += p.z; s.w += p.w;
    }
    s.x = (s.x + bias) * s2 + t2;
    s.y = (s.y + bias) * s2 + t2;
    s.z = (s.z + bias) * s2 + t2;
    s.w = (s.w + bias) * s2 + t2;
    ((float4*)C)[idx] = s;
}

// ---------------- Kernel 4: 9x9/9 maxpool with pad 4 -> yhat (89x89) ----------------
__global__ __launch_bounds__(256) void kpool(const float* __restrict__ C,
                                             float* __restrict__ yhat) {
    int idx = blockIdx.x * 256 + threadIdx.x;
    if (idx >= 89 * 89) return;
    int oy = idx / 89, ox = idx % 89;
    float mx = -INFINITY;
    int y0 = oy * 9 - 4, x0 = ox * 9 - 4;
    for (int dy = 0; dy < 9; dy++) {
        int y = y0 + dy;
        if (y < 0 || y >= 800) continue;
        for (int dx = 0; dx < 9; dx++) {
            int x = x0 + dx;
            if (x < 0 || x >= 800) continue;
            mx = fmaxf(mx, C[y * 800 + x]);
        }
    }
    yhat[idx] = mx;
}

// ---------------- Kernel 5: mean/var -> Q -> phat -> gelu ----------------
__global__ __launch_bounds__(256) void kfinal(const float* __restrict__ yhat,
                                              const float* __restrict__ gamma,
                                              float* __restrict__ out) {
    const int N = 89 * 89;
    __shared__ float sA[4], sB[4];
    int tid = threadIdx.x;
    int wid = tid >> 6, lane = tid & 63;
    float s = 0.f, ss = 0.f;
    for (int i = tid; i < N; i += 256) {
        float y = yhat[i];
        s += y;
        ss = fmaf(y, y, ss);
    }
    for (int off = 32; off; off >>= 1) {
        s += __shfl_down(s, off);
        ss += __shfl_down(ss, off);
    }
    if (lane == 0) { sA[wid] = s; sB[wid] = ss; }
    __syncthreads();
    float S = sA[0] + sA[1] + sA[2] + sA[3];
    float SS = sB[0] + sB[1] + sB[2] + sB[3];
    float mu = S / (float)N;
    float var = (SS - S * S / (float)N) / (float)(N - 1);
    float thr = mu + gamma[0] * var;
    __syncthreads();
    float q = 0.f, c = 0.f;
    for (int i = tid; i < N; i += 256) {
        float d = yhat[i] - thr;
        if (d > 0.f) { q += d; c += 1.f; }
    }
    for (int off = 32; off; off >>= 1) {
        q += __shfl_down(q, off);
        c += __shfl_down(c, off);
    }
    if (lane == 0) { sA[wid] = q; sB[wid] = c; }
    __syncthreads();
    if (tid == 0) {
        float Q = sA[0] + sA[1] + sA[2] + sA[3];
        float Cnt = sB[0] + sB[1] + sB[2] + sB[3];
        float phat = Q / (Cnt + 1.f);
        out[0] = 0.5f * phat * (1.f + erff(phat * 0.70710678118654752f));
    }
}

extern "C" void kernel_launch(void* const* d_in, const int* in_sizes, int n_in,
                              void* d_out, int out_size, void* d_ws, size_t ws_size,
                              hipStream_t stream) {
    const float* z0   = (const float*)d_in[0];
    const float* z1   = (const float*)d_in[1];
    const float* Wemb = (const float*)d_in[2];
    const float* bemb = (const float*)d_in[3];
    const float* W1   = (const float*)d_in[4];
    const float* b1   = (const float*)d_in[5];
    const float* bn1g = (const float*)d_in[6];
    const float* bn1b = (const float*)d_in[7];
    const float* bn1m = (const float*)d_in[8];
    const float* bn1v = (const float*)d_in[9];
    const float* W2   = (const float*)d_in[10];
    const float* b2   = (const float*)d_in[11];
    const float* bn2g = (const float*)d_in[12];
    const float* bn2b = (const float*)d_in[13];
    const float* bn2m = (const float*)d_in[14];
    const float* bn2v = (const float*)d_in[15];
    const float* gam  = (const float*)d_in[16];

    float* ws   = (float*)d_ws;
    float* e0   = ws;                                    // 80,000 f32
    float* e1   = ws + 80000;                            // 80,000 f32
    __hip_bfloat16* Bmap = (__hip_bfloat16*)(ws + 160000);  // 50*PLANE bf16 = 16,483,200 f32 slots
    float* Cpart = ws + 160000 + 16483200;               // 10 x 640,000 f32
    float* Cbuf  = Cpart + 6400000;                      // 640,000 f32
    float* yhat  = Cbuf + 640000;                        // 7,921 f32
    unsigned short* Bhi = (unsigned short*)(yhat + 8000);   // 16,384 u16
    unsigned short* Blo = Bhi + 16384;                      // 16,384 u16
    float* out  = (float*)d_out;

    kembed<<<200, 256, 0, stream>>>(z0, z1, Wemb, bemb, e0, e1);
    kprepW<<<64, 256, 0, stream>>>(W1, Bhi, Blo);
    kzero<<<(50 * 17696 + 255) / 256, 256, 0, stream>>>((unsigned short*)Bmap);
    dim3 gi(50, 50);
    kinter<<<gi, 256, 0, stream>>>(e0, e1, Bhi, Blo, b1, bn1g, bn1b, bn1m, bn1v, Bmap);
    dim3 gc(13, 13, 10);
    kconv<<<gc, 256, 0, stream>>>(Bmap, W2, Cpart);
    kreduce<<<(160000 + 255) / 256, 256, 0, stream>>>(Cpart, b2, bn2g, bn2b, bn2m, bn2v, Cbuf);
    kpool<<<(89 * 89 + 255) / 256, 256, 0, stream>>>(Cbuf, yhat);
    kfinal<<<1, 256, 0, stream>>>(yhat, gam, out);
}

// Round 5
// 216.463 us; speedup vs baseline: 2.8824x; 1.2099x over previous
//
#include <hip/hip_runtime.h>
#include <hip/hip_bf16.h>
#include <math.h>

#define EPS 1e-5f
#define ST 816                 // padded Bmap row stride (elems)
#define PLANE (816 * 808)      // padded plane elems

typedef _Float16 f16x2 __attribute__((ext_vector_type(2)));
typedef _Float16 f16x8 __attribute__((ext_vector_type(8)));
typedef float f32x4 __attribute__((ext_vector_type(4)));

__device__ __forceinline__ float elu_f(float x) {
    return x > 0.f ? x : __expf(x) - 1.f;
}

// ---------------- Kernel 1: e = elu(z @ W_emb^T + b_emb) ----------------
__global__ __launch_bounds__(256) void kembed(const float* __restrict__ z0,
                                              const float* __restrict__ z1,
                                              const float* __restrict__ Wemb,
                                              const float* __restrict__ bemb,
                                              float* __restrict__ e0,
                                              float* __restrict__ e1) {
    __shared__ float4 zs4[2048];  // 8 rows x 1024 floats
    int src = blockIdx.x & 1;
    int rowbase = (blockIdx.x >> 1) * 8;
    const float* z = src ? z1 : z0;
    float* e = src ? e1 : e0;
    const float4* zrow4 = reinterpret_cast<const float4*>(z + rowbase * 1024);
    for (int idx = threadIdx.x; idx < 2048; idx += 256) zs4[idx] = zrow4[idx];
    __syncthreads();
    int t = threadIdx.x;
    if (t < 200) {
        int d = t % 100;
        int half = t / 100;
        const float4* w4 = reinterpret_cast<const float4*>(Wemb + d * 1024);
        float acc[4] = {0.f, 0.f, 0.f, 0.f};
        for (int k = 0; k < 256; k++) {
            float4 w = w4[k];
#pragma unroll
            for (int r = 0; r < 4; r++) {
                float4 zv = zs4[(half * 4 + r) * 256 + k];
                acc[r] = fmaf(w.x, zv.x, acc[r]);
                acc[r] = fmaf(w.y, zv.y, acc[r]);
                acc[r] = fmaf(w.z, zv.z, acc[r]);
                acc[r] = fmaf(w.w, zv.w, acc[r]);
            }
        }
        float be = bemb[d];
#pragma unroll
        for (int r = 0; r < 4; r++) {
            e[(rowbase + half * 4 + r) * 100 + d] = elu_f(acc[r] + be);
        }
    }
}

// ---------------- Prep: pack W1 as fp16 B-fragments, d-interleaved K ----------------
// k-slot = 2*d + term (term 0 = dif, 1 = mul), K = 7*32 = 224 (d = 0..111, zero d>=100).
// Fragment order: idx = ((ks*4 + hf)*64 + lane)*8 + i
//   element: col h = hf*16 + (lane&15), k = ks*32 + (lane>>4)*8 + i
__global__ __launch_bounds__(256) void kprepW(const float* __restrict__ W1,
                                              unsigned short* __restrict__ Bh) {
    int idx = blockIdx.x * 256 + threadIdx.x;
    if (idx >= 14336) return;
    int i = idx & 7;
    int lane = (idx >> 3) & 63;
    int hf = (idx >> 9) & 3;
    int ks = idx >> 11;              // 0..6
    int h = hf * 16 + (lane & 15);
    int k = ks * 32 + (lane >> 4) * 8 + i;
    int d = k >> 1;
    int term = k & 1;
    float val = (d < 100 && h < 50) ? W1[h * 200 + term * 100 + d] : 0.f;
    _Float16 hv = (_Float16)val;
    Bh[idx] = __builtin_bit_cast(unsigned short, hv);
}

// ---------------- kzero: zero the halo borders of padded Bmap ----------------
__global__ __launch_bounds__(256) void kzero(unsigned short* __restrict__ Bmap) {
    const int per = 4896 + 12800;
    int idx = blockIdx.x * 256 + threadIdx.x;
    if (idx >= 50 * per) return;
    int h = idx / per, q = idx % per;
    int row, col;
    if (q < 4896) {
        int rr = q / 816;
        col = q - rr * 816;
        row = rr < 3 ? rr : 800 + rr;
    } else {
        int q2 = q - 4896;
        row = 3 + (q2 >> 4);
        int m = q2 & 15;
        col = m < 8 ? m : 800 + m;
    }
    Bmap[(size_t)h * PLANE + (size_t)row * ST + col] = 0;
}

// ---------------- Kernel 2: interaction GEMM via MFMA (fp16) ----------------
// grid (100,25), block 256 = 4 waves. Tile 8 i x 32 j. Wave owns 2 i (fl), 2 j-frags.
__global__ __launch_bounds__(256) void kinter(const float* __restrict__ e0,
                                              const float* __restrict__ e1,
                                              const unsigned short* __restrict__ Bh,
                                              const float* __restrict__ b1,
                                              const float* __restrict__ g1,
                                              const float* __restrict__ bb1,
                                              const float* __restrict__ m1,
                                              const float* __restrict__ v1,
                                              __hip_bfloat16* __restrict__ Bmap) {
    __shared__ float e0s[8][116];
    __shared__ float e1s[32][116];
    int i0 = blockIdx.x * 8, j0 = blockIdx.y * 32;
    int tid = threadIdx.x;
    for (int idx = tid; idx < 40 * 116; idx += 256) {
        int r = idx / 116, c = idx % 116;
        float v = 0.f;
        if (c < 100) {
            v = (r < 8) ? e0[(i0 + r) * 100 + c] : e1[(j0 + r - 8) * 100 + c];
        }
        if (r < 8) e0s[r][c] = v;
        else e1s[r - 8][c] = v;
    }
    __syncthreads();

    int lane = tid & 63;
    int wid = tid >> 6;
    int g = lane >> 4;        // k-subchunk 0..3
    int jrow = lane & 15;     // A-row = j within frag

    f32x4 acc[2][2][4] = {};  // [fl][jf][hf]

    for (int ks = 0; ks < 7; ++ks) {
        f16x8 b[4];
#pragma unroll
        for (int hf = 0; hf < 4; ++hf) {
            int fidx = ((ks * 4 + hf) * 64 + lane) * 8;
            b[hf] = __builtin_bit_cast(f16x8, *(const uint4*)(Bh + fidx));
        }
        int d0 = ks * 16 + g * 4;
        float4 x0v[2];
        x0v[0] = *(const float4*)&e0s[wid * 2 + 0][d0];
        x0v[1] = *(const float4*)&e0s[wid * 2 + 1][d0];
#pragma unroll
        for (int jf = 0; jf < 2; ++jf) {
            float4 x1 = *(const float4*)&e1s[jf * 16 + jrow][d0];
#pragma unroll
            for (int fl = 0; fl < 2; ++fl) {
                float4 x0 = x0v[fl];
                unsigned int u0 = __builtin_bit_cast(unsigned int,
                    __builtin_amdgcn_cvt_pkrtz(fabsf(x0.x - x1.x), x0.x * x1.x));
                unsigned int u1 = __builtin_bit_cast(unsigned int,
                    __builtin_amdgcn_cvt_pkrtz(fabsf(x0.y - x1.y), x0.y * x1.y));
                unsigned int u2 = __builtin_bit_cast(unsigned int,
                    __builtin_amdgcn_cvt_pkrtz(fabsf(x0.z - x1.z), x0.z * x1.z));
                unsigned int u3 = __builtin_bit_cast(unsigned int,
                    __builtin_amdgcn_cvt_pkrtz(fabsf(x0.w - x1.w), x0.w * x1.w));
                uint4 au = {u0, u1, u2, u3};
                f16x8 a = __builtin_bit_cast(f16x8, au);
#pragma unroll
                for (int hf = 0; hf < 4; ++hf) {
                    acc[fl][jf][hf] = __builtin_amdgcn_mfma_f32_16x16x32_f16(
                        a, b[hf], acc[fl][jf][hf], 0, 0, 0);
                }
            }
        }
    }

    // epilogue: D[row=j][col=h]; lane (g,hl): rows j = jf*16 + g*4 + r, col h = hf*16+hl
    int hl = lane & 15;
#pragma unroll
    for (int hf = 0; hf < 4; ++hf) {
        int h = hf * 16 + hl;
        bool ok = h < 50;
        int hc = ok ? h : 0;
        float bnb = b1[hc];
        float sc = g1[hc] * rsqrtf(v1[hc] + EPS);
        float off = bb1[hc] - m1[hc] * sc;
#pragma unroll
        for (int fl = 0; fl < 2; ++fl) {
            int i = i0 + wid * 2 + fl;
#pragma unroll
            for (int jf = 0; jf < 2; ++jf) {
                int j = j0 + jf * 16 + g * 4;
                f32x4 a = acc[fl][jf][hf];
                unsigned short o[4];
#pragma unroll
                for (int r = 0; r < 4; ++r) {
                    float x = a[r] + bnb;
                    x = elu_f(x);
                    x = fmaf(x, sc, off);
                    x = elu_f(x);
                    o[r] = __builtin_bit_cast(unsigned short, (__bf16)x);
                }
                if (ok) {
                    *(ushort4*)&Bmap[(size_t)h * PLANE + (size_t)(i + 3) * ST + (j + 8)] =
                        *(ushort4*)o;
                }
            }
        }
    }
}

// ---------------- Kernel 3: 7x7 conv, 64x64 tile, 4x4 outputs/thread ----------------
__global__ __launch_bounds__(256) void kconv(const __hip_bfloat16* __restrict__ Bmap,
                                             const float* __restrict__ W2,
                                             float* __restrict__ Cpart) {
    __shared__ float tile[70][84];
    __shared__ float w2s[49];
    int bx = blockIdx.x, by = blockIdx.y, zc = blockIdx.z;
    int h0 = zc * 5;
    int tid = threadIdx.x;
    int ly = tid >> 4, lx = tid & 15;
    float acc[4][4] = {};
    for (int hh = 0; hh < 5; ++hh) {
        int h = h0 + hh;
        __syncthreads();
        const __hip_bfloat16* plane = Bmap + (size_t)h * PLANE;
        for (int u = tid; u < 700; u += 256) {
            int r = u / 10, k = u - r * 10;
            uint4 v = *reinterpret_cast<const uint4*>(
                plane + (size_t)(64 * by + r) * ST + 64 * bx + 8 * k);
            float f[8];
            f[0] = __uint_as_float(v.x << 16);
            f[1] = __uint_as_float(v.x & 0xFFFF0000u);
            f[2] = __uint_as_float(v.y << 16);
            f[3] = __uint_as_float(v.y & 0xFFFF0000u);
            f[4] = __uint_as_float(v.z << 16);
            f[5] = __uint_as_float(v.z & 0xFFFF0000u);
            f[6] = __uint_as_float(v.w << 16);
            f[7] = __uint_as_float(v.w & 0xFFFF0000u);
            *(float4*)&tile[r][8 * k] = *(float4*)&f[0];
            *(float4*)&tile[r][8 * k + 4] = *(float4*)&f[4];
        }
        if (tid < 49) w2s[tid] = W2[h * 49 + tid];
        __syncthreads();
        float wr[49];
#pragma unroll
        for (int q = 0; q < 49; ++q) wr[q] = w2s[q];
#pragma unroll
        for (int r = 0; r < 10; ++r) {
            float w[12];
            *(float4*)&w[0] = *(const float4*)&tile[4 * ly + r][4 * lx + 4];
            *(float4*)&w[4] = *(const float4*)&tile[4 * ly + r][4 * lx + 8];
            *(float4*)&w[8] = *(const float4*)&tile[4 * ly + r][4 * lx + 12];
#pragma unroll
            for (int rr = 0; rr < 4; ++rr) {
                int di = r - rr;
                if (di < 0 || di > 6) continue;
#pragma unroll
                for (int dj = 0; dj < 7; ++dj) {
                    float wt = wr[di * 7 + dj];
#pragma unroll
                    for (int cc = 0; cc < 4; ++cc)
                        acc[rr][cc] = fmaf(w[cc + dj + 1], wt, acc[rr][cc]);
                }
            }
        }
    }
    int j = 64 * bx + 4 * lx;
    if (j < 800) {
#pragma unroll
        for (int rr = 0; rr < 4; ++rr) {
            int i = 64 * by + 4 * ly + rr;
            if (i < 800)
                *(float4*)&Cpart[(size_t)zc * 640000 + (size_t)i * 800 + j] =
                    *(float4*)acc[rr];
        }
    }
}

// ---------------- Kernel 3b: reduce partials + bias + bn2 ----------------
__global__ __launch_bounds__(256) void kreduce(const float* __restrict__ Cpart,
                                               const float* __restrict__ b2,
                                               const float* __restrict__ g2,
                                               const float* __restrict__ bb2,
                                               const float* __restrict__ m2,
                                               const float* __restrict__ v2,
                                               float* __restrict__ C) {
    int idx = blockIdx.x * 256 + threadIdx.x;
    if (idx >= 160000) return;
    float s2 = g2[0] * rsqrtf(v2[0] + EPS);
    float t2 = bb2[0] - m2[0] * s2;
    float bias = b2[0];
    float4 s = ((const float4*)Cpart)[idx];
#pragma unroll
    for (int z = 1; z < 10; z++) {
        float4 p = ((const float4*)(Cpart + (size_t)z * 640000))[idx];
        s.x += p.x; s.y += p.y; s.z += p.z; s.w += p.w;
    }
    s.x = (s.x + bias) * s2 + t2;
    s.y = (s.y + bias) * s2 + t2;
    s.z = (s.z + bias) * s2 + t2;
    s.w = (s.w + bias) * s2 + t2;
    ((float4*)C)[idx] = s;
}

// ---------------- Kernel 4: 9x9/9 maxpool with pad 4 -> yhat (89x89) ----------------
__global__ __launch_bounds__(256) void kpool(const float* __restrict__ C,
                                             float* __restrict__ yhat) {
    int idx = blockIdx.x * 256 + threadIdx.x;
    if (idx >= 89 * 89) return;
    int oy = idx / 89, ox = idx % 89;
    float mx = -INFINITY;
    int y0 = oy * 9 - 4, x0 = ox * 9 - 4;
    for (int dy = 0; dy < 9; dy++) {
        int y = y0 + dy;
        if (y < 0 || y >= 800) continue;
        for (int dx = 0; dx < 9; dx++) {
            int x = x0 + dx;
            if (x < 0 || x >= 800) continue;
            mx = fmaxf(mx, C[y * 800 + x]);
        }
    }
    yhat[idx] = mx;
}

// ---------------- Kernel 5: mean/var -> Q -> phat -> gelu ----------------
__global__ __launch_bounds__(256) void kfinal(const float* __restrict__ yhat,
                                              const float* __restrict__ gamma,
                                              float* __restrict__ out) {
    const int N = 89 * 89;
    __shared__ float sA[4], sB[4];
    int tid = threadIdx.x;
    int wid = tid >> 6, lane = tid & 63;
    float s = 0.f, ss = 0.f;
    for (int i = tid; i < N; i += 256) {
        float y = yhat[i];
        s += y;
        ss = fmaf(y, y, ss);
    }
    for (int off = 32; off; off >>= 1) {
        s += __shfl_down(s, off);
        ss += __shfl_down(ss, off);
    }
    if (lane == 0) { sA[wid] = s; sB[wid] = ss; }
    __syncthreads();
    float S = sA[0] + sA[1] + sA[2] + sA[3];
    float SS = sB[0] + sB[1] + sB[2] + sB[3];
    float mu = S / (float)N;
    float var = (SS - S * S / (float)N) / (float)(N - 1);
    float thr = mu + gamma[0] * var;
    __syncthreads();
    float q = 0.f, c = 0.f;
    for (int i = tid; i < N; i += 256) {
        float d = yhat[i] - thr;
        if (d > 0.f) { q += d; c += 1.f; }
    }
    for (int off = 32; off; off >>= 1) {
        q += __shfl_down(q, off);
        c += __shfl_down(c, off);
    }
    if (lane == 0) { sA[wid] = q; sB[wid] = c; }
    __syncthreads();
    if (tid == 0) {
        float Q = sA[0] + sA[1] + sA[2] + sA[3];
        float Cnt = sB[0] + sB[1] + sB[2] + sB[3];
        float phat = Q / (Cnt + 1.f);
        out[0] = 0.5f * phat * (1.f + erff(phat * 0.70710678118654752f));
    }
}

extern "C" void kernel_launch(void* const* d_in, const int* in_sizes, int n_in,
                              void* d_out, int out_size, void* d_ws, size_t ws_size,
                              hipStream_t stream) {
    const float* z0   = (const float*)d_in[0];
    const float* z1   = (const float*)d_in[1];
    const float* Wemb = (const float*)d_in[2];
    const float* bemb = (const float*)d_in[3];
    const float* W1   = (const float*)d_in[4];
    const float* b1   = (const float*)d_in[5];
    const float* bn1g = (const float*)d_in[6];
    const float* bn1b = (const float*)d_in[7];
    const float* bn1m = (const float*)d_in[8];
    const float* bn1v = (const float*)d_in[9];
    const float* W2   = (const float*)d_in[10];
    const float* b2   = (const float*)d_in[11];
    const float* bn2g = (const float*)d_in[12];
    const float* bn2b = (const float*)d_in[13];
    const float* bn2m = (const float*)d_in[14];
    const float* bn2v = (const float*)d_in[15];
    const float* gam  = (const float*)d_in[16];

    float* ws   = (float*)d_ws;
    float* e0   = ws;                                    // 80,000 f32
    float* e1   = ws + 80000;                            // 80,000 f32
    __hip_bfloat16* Bmap = (__hip_bfloat16*)(ws + 160000);  // 50*PLANE bf16
    float* Cpart = ws + 160000 + 16483200;               // 10 x 640,000 f32
    float* Cbuf  = Cpart + 6400000;                      // 640,000 f32
    float* yhat  = Cbuf + 640000;                        // 7,921 f32
    unsigned short* Bh = (unsigned short*)(yhat + 8000); // 14,336 u16
    float* out  = (float*)d_out;

    kembed<<<200, 256, 0, stream>>>(z0, z1, Wemb, bemb, e0, e1);
    kprepW<<<56, 256, 0, stream>>>(W1, Bh);
    kzero<<<(50 * 17696 + 255) / 256, 256, 0, stream>>>((unsigned short*)Bmap);
    dim3 gi(100, 25);
    kinter<<<gi, 256, 0, stream>>>(e0, e1, Bh, b1, bn1g, bn1b, bn1m, bn1v, Bmap);
    dim3 gc(13, 13, 10);
    kconv<<<gc, 256, 0, stream>>>(Bmap, W2, Cpart);
    kreduce<<<(160000 + 255) / 256, 256, 0, stream>>>(Cpart, b2, bn2g, bn2b, bn2m, bn2v, Cbuf);
    kpool<<<(89 * 89 + 255) / 256, 256, 0, stream>>>(Cbuf, yhat);
    kfinal<<<1, 256, 0, stream>>>(yhat, gam, out);
}

// Round 6
// 213.122 us; speedup vs baseline: 2.9276x; 1.0157x over previous
//
#include <hip/hip_runtime.h>
#include <hip/hip_bf16.h>
#include <math.h>

#define EPS 1e-5f
#define ST 816                 // padded Bmap row stride (elems)
#define PLANE (816 * 808)      // padded plane elems

typedef _Float16 f16x8 __attribute__((ext_vector_type(8)));
typedef float f32x4 __attribute__((ext_vector_type(4)));

__device__ __forceinline__ float elu_f(float x) {
    return x > 0.f ? x : __expf(x) - 1.f;
}

// ---------------- Kernel 1: e = elu(z @ W_emb^T + b_emb) ----------------
__global__ __launch_bounds__(256) void kembed(const float* __restrict__ z0,
                                              const float* __restrict__ z1,
                                              const float* __restrict__ Wemb,
                                              const float* __restrict__ bemb,
                                              float* __restrict__ e0,
                                              float* __restrict__ e1) {
    __shared__ float4 zs4[2048];  // 8 rows x 1024 floats
    int src = blockIdx.x & 1;
    int rowbase = (blockIdx.x >> 1) * 8;
    const float* z = src ? z1 : z0;
    float* e = src ? e1 : e0;
    const float4* zrow4 = reinterpret_cast<const float4*>(z + rowbase * 1024);
    for (int idx = threadIdx.x; idx < 2048; idx += 256) zs4[idx] = zrow4[idx];
    __syncthreads();
    int t = threadIdx.x;
    if (t < 200) {
        int d = t % 100;
        int half = t / 100;
        const float4* w4 = reinterpret_cast<const float4*>(Wemb + d * 1024);
        float acc[4] = {0.f, 0.f, 0.f, 0.f};
        for (int k = 0; k < 256; k++) {
            float4 w = w4[k];
#pragma unroll
            for (int r = 0; r < 4; r++) {
                float4 zv = zs4[(half * 4 + r) * 256 + k];
                acc[r] = fmaf(w.x, zv.x, acc[r]);
                acc[r] = fmaf(w.y, zv.y, acc[r]);
                acc[r] = fmaf(w.z, zv.z, acc[r]);
                acc[r] = fmaf(w.w, zv.w, acc[r]);
            }
        }
        float be = bemb[d];
#pragma unroll
        for (int r = 0; r < 4; r++) {
            e[(rowbase + half * 4 + r) * 100 + d] = elu_f(acc[r] + be);
        }
    }
}

// ---------------- Prep: pack W1 as fp16 B-fragments, d-interleaved K ----------------
__global__ __launch_bounds__(256) void kprepW(const float* __restrict__ W1,
                                              unsigned short* __restrict__ Bh) {
    int idx = blockIdx.x * 256 + threadIdx.x;
    if (idx >= 14336) return;
    int i = idx & 7;
    int lane = (idx >> 3) & 63;
    int hf = (idx >> 9) & 3;
    int ks = idx >> 11;              // 0..6
    int h = hf * 16 + (lane & 15);
    int k = ks * 32 + (lane >> 4) * 8 + i;
    int d = k >> 1;
    int term = k & 1;
    float val = (d < 100 && h < 50) ? W1[h * 200 + term * 100 + d] : 0.f;
    _Float16 hv = (_Float16)val;
    Bh[idx] = __builtin_bit_cast(unsigned short, hv);
}

// ---------------- kzero: zero the halo borders of padded Bmap ----------------
__global__ __launch_bounds__(256) void kzero(unsigned short* __restrict__ Bmap) {
    const int per = 4896 + 12800;
    int idx = blockIdx.x * 256 + threadIdx.x;
    if (idx >= 50 * per) return;
    int h = idx / per, q = idx % per;
    int row, col;
    if (q < 4896) {
        int rr = q / 816;
        col = q - rr * 816;
        row = rr < 3 ? rr : 800 + rr;
    } else {
        int q2 = q - 4896;
        row = 3 + (q2 >> 4);
        int m = q2 & 15;
        col = m < 8 ? m : 800 + m;
    }
    Bmap[(size_t)h * PLANE + (size_t)row * ST + col] = 0;
}

// ---------------- Kernel 2: interaction GEMM via MFMA (fp16) ----------------
// grid (100,25), block 256 = 4 waves. Tile 8 i x 32 j. Wave owns 2 i (fl), 2 j-frags.
__global__ __launch_bounds__(256) void kinter(const float* __restrict__ e0,
                                              const float* __restrict__ e1,
                                              const unsigned short* __restrict__ Bh,
                                              const float* __restrict__ b1,
                                              const float* __restrict__ g1,
                                              const float* __restrict__ bb1,
                                              const float* __restrict__ m1,
                                              const float* __restrict__ v1,
                                              __hip_bfloat16* __restrict__ Bmap) {
    __shared__ float e0s[8][116];
    __shared__ float e1s[32][116];
    int i0 = blockIdx.x * 8, j0 = blockIdx.y * 32;
    int tid = threadIdx.x;
    for (int idx = tid; idx < 40 * 116; idx += 256) {
        int r = idx / 116, c = idx % 116;
        float v = 0.f;
        if (c < 100) {
            v = (r < 8) ? e0[(i0 + r) * 100 + c] : e1[(j0 + r - 8) * 100 + c];
        }
        if (r < 8) e0s[r][c] = v;
        else e1s[r - 8][c] = v;
    }
    __syncthreads();

    int lane = tid & 63;
    int wid = tid >> 6;
    int g = lane >> 4;        // k-subchunk 0..3
    int jrow = lane & 15;     // A-row = j within frag

    f32x4 acc[2][2][4] = {};  // [fl][jf][hf]

    for (int ks = 0; ks < 7; ++ks) {
        f16x8 b[4];
#pragma unroll
        for (int hf = 0; hf < 4; ++hf) {
            int fidx = ((ks * 4 + hf) * 64 + lane) * 8;
            b[hf] = __builtin_bit_cast(f16x8, *(const uint4*)(Bh + fidx));
        }
        int d0 = ks * 16 + g * 4;
        float4 x0v[2];
        x0v[0] = *(const float4*)&e0s[wid * 2 + 0][d0];
        x0v[1] = *(const float4*)&e0s[wid * 2 + 1][d0];
#pragma unroll
        for (int jf = 0; jf < 2; ++jf) {
            float4 x1 = *(const float4*)&e1s[jf * 16 + jrow][d0];
#pragma unroll
            for (int fl = 0; fl < 2; ++fl) {
                float4 x0 = x0v[fl];
                unsigned int u0 = __builtin_bit_cast(unsigned int,
                    __builtin_amdgcn_cvt_pkrtz(fabsf(x0.x - x1.x), x0.x * x1.x));
                unsigned int u1 = __builtin_bit_cast(unsigned int,
                    __builtin_amdgcn_cvt_pkrtz(fabsf(x0.y - x1.y), x0.y * x1.y));
                unsigned int u2 = __builtin_bit_cast(unsigned int,
                    __builtin_amdgcn_cvt_pkrtz(fabsf(x0.z - x1.z), x0.z * x1.z));
                unsigned int u3 = __builtin_bit_cast(unsigned int,
                    __builtin_amdgcn_cvt_pkrtz(fabsf(x0.w - x1.w), x0.w * x1.w));
                uint4 au = {u0, u1, u2, u3};
                f16x8 a = __builtin_bit_cast(f16x8, au);
#pragma unroll
                for (int hf = 0; hf < 4; ++hf) {
                    acc[fl][jf][hf] = __builtin_amdgcn_mfma_f32_16x16x32_f16(
                        a, b[hf], acc[fl][jf][hf], 0, 0, 0);
                }
            }
        }
    }

    // epilogue: D[row=j][col=h]; lane (g,hl): rows j = jf*16 + g*4 + r, col h = hf*16+hl
    int hl = lane & 15;
#pragma unroll
    for (int hf = 0; hf < 4; ++hf) {
        int h = hf * 16 + hl;
        bool ok = h < 50;
        int hc = ok ? h : 0;
        float bnb = b1[hc];
        float sc = g1[hc] * rsqrtf(v1[hc] + EPS);
        float off = bb1[hc] - m1[hc] * sc;
#pragma unroll
        for (int fl = 0; fl < 2; ++fl) {
            int i = i0 + wid * 2 + fl;
#pragma unroll
            for (int jf = 0; jf < 2; ++jf) {
                int j = j0 + jf * 16 + g * 4;
                f32x4 a = acc[fl][jf][hf];
                unsigned short o[4];
#pragma unroll
                for (int r = 0; r < 4; ++r) {
                    float x = a[r] + bnb;
                    x = elu_f(x);
                    x = fmaf(x, sc, off);
                    x = elu_f(x);
                    o[r] = __builtin_bit_cast(unsigned short, (__bf16)x);
                }
                if (ok) {
                    *(ushort4*)&Bmap[(size_t)h * PLANE + (size_t)(i + 3) * ST + (j + 8)] =
                        *(ushort4*)o;
                }
            }
        }
    }
}

// ---------------- Kernel 3: 7x7 conv, 64i x 32j tile, 128 thr, 4x4 out/thread ----------------
// grid (25 j-tiles, 13 i-tiles, 10 ch-chunks). LDS tile stride 50 (b64-aligned).
__global__ __launch_bounds__(128, 4) void kconv(const __hip_bfloat16* __restrict__ Bmap,
                                                const float* __restrict__ W2,
                                                float* __restrict__ Cpart) {
    __shared__ float tile[70][50];
    __shared__ float w2s[49];
    int bx = blockIdx.x, by = blockIdx.y, zc = blockIdx.z;
    int h0 = zc * 5;
    int tid = threadIdx.x;
    int lx = tid & 7, ly = tid >> 3;      // 8 x 16 threads
    float acc[4][4] = {};
    for (int hh = 0; hh < 5; ++hh) {
        int h = h0 + hh;
        __syncthreads();
        const __hip_bfloat16* plane = Bmap + (size_t)h * PLANE;
        // stage 70 rows x 48 cols (6 x uint4 of 8 bf16 per row), aligned, no branches
        for (int u = tid; u < 420; u += 128) {
            int r = u / 6, k = u - r * 6;
            uint4 v = *reinterpret_cast<const uint4*>(
                plane + (size_t)(64 * by + r) * ST + 32 * bx + 8 * k);
            float f[8];
            f[0] = __uint_as_float(v.x << 16);
            f[1] = __uint_as_float(v.x & 0xFFFF0000u);
            f[2] = __uint_as_float(v.y << 16);
            f[3] = __uint_as_float(v.y & 0xFFFF0000u);
            f[4] = __uint_as_float(v.z << 16);
            f[5] = __uint_as_float(v.z & 0xFFFF0000u);
            f[6] = __uint_as_float(v.w << 16);
            f[7] = __uint_as_float(v.w & 0xFFFF0000u);
            *(float2*)&tile[r][8 * k + 0] = *(float2*)&f[0];
            *(float2*)&tile[r][8 * k + 2] = *(float2*)&f[2];
            *(float2*)&tile[r][8 * k + 4] = *(float2*)&f[4];
            *(float2*)&tile[r][8 * k + 6] = *(float2*)&f[6];
        }
        if (tid < 49) w2s[tid] = W2[h * 49 + tid];
        __syncthreads();
        float wr[49];
#pragma unroll
        for (int q = 0; q < 49; ++q) wr[q] = w2s[q];
#pragma unroll
        for (int r = 0; r < 10; ++r) {
            float w[12];
#pragma unroll
            for (int t = 0; t < 6; ++t)
                *(float2*)&w[2 * t] = *(const float2*)&tile[4 * ly + r][4 * lx + 4 + 2 * t];
#pragma unroll
            for (int rr = 0; rr < 4; ++rr) {
                int di = r - rr;
                if (di < 0 || di > 6) continue;
#pragma unroll
                for (int dj = 0; dj < 7; ++dj) {
                    float wt = wr[di * 7 + dj];
#pragma unroll
                    for (int cc = 0; cc < 4; ++cc)
                        acc[rr][cc] = fmaf(w[cc + dj + 1], wt, acc[rr][cc]);
                }
            }
        }
    }
    int j = 32 * bx + 4 * lx;
#pragma unroll
    for (int rr = 0; rr < 4; ++rr) {
        int i = 64 * by + 4 * ly + rr;
        if (i < 800)
            *(float4*)&Cpart[(size_t)zc * 640000 + (size_t)i * 800 + j] =
                *(float4*)acc[rr];
    }
}

// ---------------- Kernel 3b: reduce partials + bias + bn2 ----------------
__global__ __launch_bounds__(256) void kreduce(const float* __restrict__ Cpart,
                                               const float* __restrict__ b2,
                                               const float* __restrict__ g2,
                                               const float* __restrict__ bb2,
                                               const float* __restrict__ m2,
                                               const float* __restrict__ v2,
                                               float* __restrict__ C) {
    int idx = blockIdx.x * 256 + threadIdx.x;
    if (idx >= 160000) return;
    float s2 = g2[0] * rsqrtf(v2[0] + EPS);
    float t2 = bb2[0] - m2[0] * s2;
    float bias = b2[0];
    float4 s = ((const float4*)Cpart)[idx];
#pragma unroll
    for (int z = 1; z < 10; z++) {
        float4 p = ((const float4*)(Cpart + (size_t)z * 640000))[idx];
        s.x += p.x; s.y += p.y; s.z += p.z; s.w += p.w;
    }
    s.x = (s.x + bias) * s2 + t2;
    s.y = (s.y + bias) * s2 + t2;
    s.z = (s.z + bias) * s2 + t2;
    s.w = (s.w + bias) * s2 + t2;
    ((float4*)C)[idx] = s;
}

// ---------------- Kernel 4: 9x9/9 maxpool with pad 4 -> yhat (89x89) ----------------
__global__ __launch_bounds__(256) void kpool(const float* __restrict__ C,
                                             float* __restrict__ yhat) {
    int idx = blockIdx.x * 256 + threadIdx.x;
    if (idx >= 89 * 89) return;
    int oy = idx / 89, ox = idx % 89;
    float mx = -INFINITY;
    int y0 = oy * 9 - 4, x0 = ox * 9 - 4;
    for (int dy = 0; dy < 9; dy++) {
        int y = y0 + dy;
        if (y < 0 || y >= 800) continue;
        for (int dx = 0; dx < 9; dx++) {
            int x = x0 + dx;
            if (x < 0 || x >= 800) continue;
            mx = fmaxf(mx, C[y * 800 + x]);
        }
    }
    yhat[idx] = mx;
}

// ---------------- Kernel 5: mean/var -> Q -> phat -> gelu ----------------
__global__ __launch_bounds__(256) void kfinal(const float* __restrict__ yhat,
                                              const float* __restrict__ gamma,
                                              float* __restrict__ out) {
    const int N = 89 * 89;
    __shared__ float sA[4], sB[4];
    int tid = threadIdx.x;
    int wid = tid >> 6, lane = tid & 63;
    float s = 0.f, ss = 0.f;
    for (int i = tid; i < N; i += 256) {
        float y = yhat[i];
        s += y;
        ss = fmaf(y, y, ss);
    }
    for (int off = 32; off; off >>= 1) {
        s += __shfl_down(s, off);
        ss += __shfl_down(ss, off);
    }
    if (lane == 0) { sA[wid] = s; sB[wid] = ss; }
    __syncthreads();
    float S = sA[0] + sA[1] + sA[2] + sA[3];
    float SS = sB[0] + sB[1] + sB[2] + sB[3];
    float mu = S / (float)N;
    float var = (SS - S * S / (float)N) / (float)(N - 1);
    float thr = mu + gamma[0] * var;
    __syncthreads();
    float q = 0.f, c = 0.f;
    for (int i = tid; i < N; i += 256) {
        float d = yhat[i] - thr;
        if (d > 0.f) { q += d; c += 1.f; }
    }
    for (int off = 32; off; off >>= 1) {
        q += __shfl_down(q, off);
        c += __shfl_down(c, off);
    }
    if (lane == 0) { sA[wid] = q; sB[wid] = c; }
    __syncthreads();
    if (tid == 0) {
        float Q = sA[0] + sA[1] + sA[2] + sA[3];
        float Cnt = sB[0] + sB[1] + sB[2] + sB[3];
        float phat = Q / (Cnt + 1.f);
        out[0] = 0.5f * phat * (1.f + erff(phat * 0.70710678118654752f));
    }
}

extern "C" void kernel_launch(void* const* d_in, const int* in_sizes, int n_in,
                              void* d_out, int out_size, void* d_ws, size_t ws_size,
                              hipStream_t stream) {
    const float* z0   = (const float*)d_in[0];
    const float* z1   = (const float*)d_in[1];
    const float* Wemb = (const float*)d_in[2];
    const float* bemb = (const float*)d_in[3];
    const float* W1   = (const float*)d_in[4];
    const float* b1   = (const float*)d_in[5];
    const float* bn1g = (const float*)d_in[6];
    const float* bn1b = (const float*)d_in[7];
    const float* bn1m = (const float*)d_in[8];
    const float* bn1v = (const float*)d_in[9];
    const float* W2   = (const float*)d_in[10];
    const float* b2   = (const float*)d_in[11];
    const float* bn2g = (const float*)d_in[12];
    const float* bn2b = (const float*)d_in[13];
    const float* bn2m = (const float*)d_in[14];
    const float* bn2v = (const float*)d_in[15];
    const float* gam  = (const float*)d_in[16];

    float* ws   = (float*)d_ws;
    float* e0   = ws;                                    // 80,000 f32
    float* e1   = ws + 80000;                            // 80,000 f32
    __hip_bfloat16* Bmap = (__hip_bfloat16*)(ws + 160000);  // 50*PLANE bf16
    float* Cpart = ws + 160000 + 16483200;               // 10 x 640,000 f32
    float* Cbuf  = Cpart + 6400000;                      // 640,000 f32
    float* yhat  = Cbuf + 640000;                        // 7,921 f32
    unsigned short* Bh = (unsigned short*)(yhat + 8000); // 14,336 u16
    float* out  = (float*)d_out;

    kembed<<<200, 256, 0, stream>>>(z0, z1, Wemb, bemb, e0, e1);
    kprepW<<<56, 256, 0, stream>>>(W1, Bh);
    kzero<<<(50 * 17696 + 255) / 256, 256, 0, stream>>>((unsigned short*)Bmap);
    dim3 gi(100, 25);
    kinter<<<gi, 256, 0, stream>>>(e0, e1, Bh, b1, bn1g, bn1b, bn1m, bn1v, Bmap);
    dim3 gc(25, 13, 10);
    kconv<<<gc, 128, 0, stream>>>(Bmap, W2, Cpart);
    kreduce<<<(160000 + 255) / 256, 256, 0, stream>>>(Cpart, b2, bn2g, bn2b, bn2m, bn2v, Cbuf);
    kpool<<<(89 * 89 + 255) / 256, 256, 0, stream>>>(Cbuf, yhat);
    kfinal<<<1, 256, 0, stream>>>(yhat, gam, out);
}